// Round 1
// baseline (463.081 us; speedup 1.0000x reference)
//
#include <hip/hip_runtime.h>
#include <hip/hip_bf16.h>

typedef __hip_bfloat16 bf16;
typedef __attribute__((ext_vector_type(8))) short s8v;      // 8 bf16 (4 VGPRs) MFMA A/B frag
typedef __attribute__((ext_vector_type(4))) float f32x4;    // MFMA C/D frag

__device__ __forceinline__ float bits2f(unsigned short u) {
    return __uint_as_float(((unsigned)u) << 16);
}
__device__ __forceinline__ unsigned short f2b(float f) {   // fp32 -> bf16 RNE
    union { float f; unsigned u; } x{f};
    return (unsigned short)((x.u + 0x7fff + ((x.u >> 16) & 1)) >> 16);
}
__device__ __forceinline__ float to_f(float x) { return x; }
__device__ __forceinline__ float to_f(unsigned short x) { return bits2f(x); }

__device__ __forceinline__ void load4(const float* p, float* a) {
    float4 t = *(const float4*)p;
    a[0] = t.x; a[1] = t.y; a[2] = t.z; a[3] = t.w;
}
__device__ __forceinline__ void load4(const unsigned short* p, float* a) {
    ushort4 t = *(const ushort4*)p;
    a[0] = bits2f(t.x); a[1] = bits2f(t.y); a[2] = bits2f(t.z); a[3] = bits2f(t.w);
}

// ---------------- fused fp32 -> bf16 convert of x + all weights ----------------
__global__ __launch_bounds__(256)
void cvt_all_kernel(const float* __restrict__ x,
                    const float* __restrict__ Wq, const float* __restrict__ Wk,
                    const float* __restrict__ Wv, const float* __restrict__ Wo,
                    const float* __restrict__ W1, const float* __restrict__ W2,
                    unsigned short* __restrict__ xb, unsigned short* __restrict__ Wqkvb,
                    unsigned short* __restrict__ Wob,
                    unsigned short* __restrict__ W1b, unsigned short* __restrict__ W2b)
{
    int i = blockIdx.x * 256 + threadIdx.x;
    const float* src; unsigned short* dst; int off;
    if (i < (1 << 20))      { src = x;  dst = xb;  off = i; }
    else if (i < (2 << 20)) { src = W1; dst = W1b; off = i - (1 << 20); }
    else if (i < (3 << 20)) { src = W2; dst = W2b; off = i - (2 << 20); }
    else {
        int j = i - (3 << 20);
        int sel = j >> 18;
        off = j & ((1 << 18) - 1);
        src = sel == 0 ? Wq : sel == 1 ? Wk : sel == 2 ? Wv : Wo;
        dst = sel == 3 ? Wob : Wqkvb + ((size_t)sel << 20);
    }
    float4 v = ((const float4*)src)[off];
    ushort4 o = { f2b(v.x), f2b(v.y), f2b(v.z), f2b(v.w) };
    ((ushort4*)dst)[off] = o;
}

// ---------------- per-head relative-position bias by delta (T5 buckets, double math) ----------------
__global__ void rbias_kernel(const float* __restrict__ rel_emb, unsigned short* __restrict__ rbias)
{
    int idx = blockIdx.x * 256 + threadIdx.x;   // 16 * 2048
    if (idx >= 16 * 2048) return;
    int h = idx >> 11, q = idx & 2047;
    int n = q - 1023, ret = 0;                  // n = j - i
    if (n < 0) { ret = 16; n = -n; }
    int b;
    if (n < 8) b = n;
    else {
        double t = log((double)n / 8.0) / log(16.0) * 8.0;
        int v = 8 + (int)t;
        b = v < 15 ? v : 15;
    }
    rbias[idx] = f2b(rel_emb[(ret + b) * 16 + h]);
}

// ---------------- legacy MFMA GEMM (kept for Wo projection only) ----------------
template<typename TC, typename TR, int RELU, int QKV>
__global__ __launch_bounds__(256)
void mfma_gemm(const unsigned short* __restrict__ A, int lda,
               const unsigned short* __restrict__ W, int ldw,
               const float* __restrict__ b0, const float* __restrict__ b1,
               const float* __restrict__ b2,
               const TR* __restrict__ res,
               void* __restrict__ C0, void* __restrict__ C1, void* __restrict__ C2,
               int ldc, int M, int N, int Ksplit)
{
    __shared__ unsigned short sm[2 * 128 * 32];
    unsigned short* As = sm;
    unsigned short* Ws = sm + 128 * 32;

    const int tid = threadIdx.x;
    const int w = tid >> 6, lane = tid & 63;
    const int quad = lane >> 4, col = lane & 15;
    const int m0 = blockIdx.y * 128, n0 = blockIdx.x * 128;
    const int wrow = (w & 1) * 64, wcol = (w >> 1) * 64;
    const int kz = blockIdx.z * Ksplit;

    const int srow   = lane >> 2;
    const int schunk = (lane & 3) ^ ((lane >> 4) & 3);

    f32x4 acc[4][4] = {};

    for (int k0 = kz; k0 < kz + Ksplit; k0 += 32) {
        __syncthreads();
        #pragma unroll
        for (int t = 0; t < 2; ++t) {
            const int rbase = w * 32 + t * 16;
            unsigned off = (unsigned)(rbase * 64);
            off = __builtin_amdgcn_readfirstlane(off);
            const unsigned short* ga = A + (size_t)(m0 + rbase + srow) * lda + k0 + schunk * 8;
            __builtin_amdgcn_global_load_lds(
                (const __attribute__((address_space(1))) unsigned int*)ga,
                (__attribute__((address_space(3))) unsigned int*)((char*)As + off), 16, 0, 0);
            const unsigned short* gw = W + (size_t)(n0 + rbase + srow) * ldw + k0 + schunk * 8;
            __builtin_amdgcn_global_load_lds(
                (const __attribute__((address_space(1))) unsigned int*)gw,
                (__attribute__((address_space(3))) unsigned int*)((char*)Ws + off), 16, 0, 0);
        }
        __syncthreads();

        s8v af[4], bfr[4];
        #pragma unroll
        for (int mt = 0; mt < 4; ++mt) {
            int rr = wrow + mt * 16 + col;
            af[mt] = *(const s8v*)(As + rr * 32 + ((quad ^ ((rr >> 2) & 3)) * 8));
        }
        #pragma unroll
        for (int nt = 0; nt < 4; ++nt) {
            int rr = wcol + nt * 16 + col;
            bfr[nt] = *(const s8v*)(Ws + rr * 32 + ((quad ^ ((rr >> 2) & 3)) * 8));
        }
        #pragma unroll
        for (int mt = 0; mt < 4; ++mt)
            #pragma unroll
            for (int nt = 0; nt < 4; ++nt)
                acc[mt][nt] = __builtin_amdgcn_mfma_f32_16x16x32_bf16(af[mt], bfr[nt], acc[mt][nt], 0, 0, 0);
    }

    if (QKV) {
        const int sel = n0 >> 10;
        unsigned short* Cb = (unsigned short*)(sel == 0 ? C0 : sel == 1 ? C1 : C2);
        const float* bs = sel == 0 ? b0 : sel == 1 ? b1 : b2;
        #pragma unroll
        for (int mt = 0; mt < 4; ++mt)
            #pragma unroll
            for (int rg = 0; rg < 4; ++rg) {
                int gm = m0 + wrow + mt * 16 + quad * 4 + rg;
                #pragma unroll
                for (int nt = 0; nt < 4; ++nt) {
                    int gnc = (n0 + wcol + nt * 16 + col) & 1023;
                    Cb[(size_t)gm * 1024 + gnc] = f2b(acc[mt][nt][rg] + bs[gnc]);
                }
            }
    } else {
        void* Cv = blockIdx.z ? C1 : C0;
        const bool z0 = (blockIdx.z == 0);
        #pragma unroll
        for (int mt = 0; mt < 4; ++mt)
            #pragma unroll
            for (int rg = 0; rg < 4; ++rg) {
                int gm = m0 + wrow + mt * 16 + quad * 4 + rg;
                #pragma unroll
                for (int nt = 0; nt < 4; ++nt) {
                    int gn = n0 + wcol + nt * 16 + col;
                    float c = acc[mt][nt][rg];
                    if (z0) {
                        if (b0)  c += b0[gn];
                        if (res) c += to_f(res[(size_t)gm * ldc + gn]);
                    }
                    if (RELU) c = fmaxf(c, 0.f);
                    if (sizeof(TC) == 2) ((unsigned short*)Cv)[(size_t)gm * ldc + gn] = f2b(c);
                    else                 ((float*)Cv)[(size_t)gm * ldc + gn] = c;
                }
            }
    }
}

// ================= 256x256 8-phase counted-vmcnt GEMM (T2+T3+T4+T5) =================
// C[m][n] = sum_k A[m][k] * W[n][k], A/W bf16 row-major K-contiguous.
// 512 threads = 8 waves (wm in 0..1, wn in 0..3); per-wave 128x64 output as
// interleaved 16-row fragments: C row = m0 + mt*32 + wm*16 + quad*4 + rg,
//                               C col = n0 + nt*64 + wn*16 + col.
// LDS 128KB dynamic: A dbuf [2][256][64] + B dbuf [2][256][64] bf16.
// Per K-tile (BK=64): 4 phases in region order (A0B0)(A0B1)(A1B1)(A1B0);
// staging: ph0->B0(t+1), ph1->A1(t+1) [other buffer],
//          ph2->A0(t+2), ph3->B1(t+2) [current buffer, region dead by then].
// vmcnt(4) once per tile boundary (2 half-tiles always in flight), never 0
// in steady state. Raw s_barrier (no implicit vmcnt drain).

// per-row chunk XOR: spreads the 4 quad-chunks of a ds_read_b128 over all 8
// column-chunks (all 32 banks) across the 16 rows an instruction touches.
#define SWZ(r) ((((r) >> 2) & 3) | ((((r) >> 2) & 1) << 2))

__device__ __forceinline__ void stage_ht(const unsigned short* __restrict__ g, int ld,
                                         int grow0, int kbase,
                                         unsigned short* lds_half, int tid)
{
    // one 128x64 bf16 half-tile: 2 x global_load_lds(16B) per thread, linear LDS
    // dest; source pre-swizzled so swizzled ds_reads see the right data (rule 21).
    #pragma unroll
    for (int l = 0; l < 2; ++l) {
        int idx = l * 512 + tid;
        int r = idx >> 3;
        int c = (idx & 7) ^ SWZ(r);
        const unsigned short* src = g + (size_t)(grow0 + r) * ld + kbase + c * 8;
        unsigned off = (unsigned)__builtin_amdgcn_readfirstlane((unsigned)((l * 512 + (tid & 448)) * 16));
        __builtin_amdgcn_global_load_lds(
            (const __attribute__((address_space(1))) unsigned int*)src,
            (__attribute__((address_space(3))) unsigned int*)((char*)lds_half + off), 16, 0, 0);
    }
}

#define PHASE(HM, HN, ...)                                                        \
    {                                                                             \
        __builtin_amdgcn_sched_barrier(0);                                        \
        s8v a_[4][2], b_[2][2];                                                   \
        _Pragma("unroll")                                                         \
        for (int mt2 = 0; mt2 < 4; ++mt2) {                                       \
            int r = ((HM) * 4 + mt2) * 32 + wm16 + col;                           \
            _Pragma("unroll")                                                     \
            for (int ks = 0; ks < 2; ++ks)                                        \
                a_[mt2][ks] = *(const s8v*)(dA + r * 64 + (((ks * 4 + quad) ^ SWZ(r)) << 3)); \
        }                                                                         \
        _Pragma("unroll")                                                         \
        for (int nt2 = 0; nt2 < 2; ++nt2) {                                       \
            int r = ((HN) * 2 + nt2) * 64 + wn16 + col;                           \
            _Pragma("unroll")                                                     \
            for (int ks = 0; ks < 2; ++ks)                                        \
                b_[nt2][ks] = *(const s8v*)(dB + r * 64 + (((ks * 4 + quad) ^ SWZ(r)) << 3)); \
        }                                                                         \
        __VA_ARGS__;                                                              \
        __builtin_amdgcn_sched_barrier(0);                                        \
        __builtin_amdgcn_s_barrier();                                             \
        asm volatile("s_waitcnt lgkmcnt(0)" ::: "memory");                        \
        __builtin_amdgcn_sched_barrier(0);                                        \
        __builtin_amdgcn_s_setprio(1);                                            \
        _Pragma("unroll")                                                         \
        for (int ks = 0; ks < 2; ++ks)                                            \
            _Pragma("unroll")                                                     \
            for (int mt2 = 0; mt2 < 4; ++mt2)                                     \
                _Pragma("unroll")                                                 \
                for (int nt2 = 0; nt2 < 2; ++nt2)                                 \
                    acc[(HM) * 4 + mt2][(HN) * 2 + nt2] =                         \
                        __builtin_amdgcn_mfma_f32_16x16x32_bf16(                  \
                            a_[mt2][ks], b_[nt2][ks], acc[(HM) * 4 + mt2][(HN) * 2 + nt2], 0, 0, 0); \
        __builtin_amdgcn_s_setprio(0);                                            \
        __builtin_amdgcn_sched_barrier(0);                                        \
    }

// MODE 0: QKV route by n-segment (bias bq/bk/bv, bf16 out ldc=1024)
// MODE 1: ff1 bias+relu, bf16 out ldc=4096
// MODE 2: ff2 split-K z: z0 adds bias+bf16 residual; bf16 partial out ldc=1024
template<int MODE>
__global__ __launch_bounds__(512, 2)
void gemm256(const unsigned short* __restrict__ A, int lda,
             const unsigned short* __restrict__ W, int ldw,
             const float* __restrict__ bias0, const float* __restrict__ bias1,
             const float* __restrict__ bias2,
             const unsigned short* __restrict__ res,
             unsigned short* __restrict__ C0, unsigned short* __restrict__ C1,
             unsigned short* __restrict__ C2,
             int NT, int Ksplit)
{
    extern __shared__ unsigned short sm[];
    unsigned short* As0 = sm;            // [2][256*64]
    unsigned short* Bs0 = sm + 32768;    // [2][256*64]

    const int tid = threadIdx.x;
    const int w = tid >> 6, lane = tid & 63;
    const int quad = lane >> 4, col = lane & 15;
    const int wm16 = (w & 1) * 16, wn16 = (w >> 1) * 16;

    // XCD-bijective swizzle (nwg % 8 == 0 for all launches here)
    const int bid = blockIdx.x + gridDim.x * blockIdx.y;
    const int nwg = gridDim.x * gridDim.y;
    const int swz = (bid & 7) * (nwg >> 3) + (bid >> 3);
    const int m0 = (swz / gridDim.x) * 256;
    const int n0 = (swz % gridDim.x) * 256;
    const int kz = blockIdx.z * Ksplit;

    f32x4 acc[8][4] = {};

    // prologue: tile0 fully + A0/B1 of tile1 (ages match steady-state invariant)
    stage_ht(A, lda, m0,       kz,      As0,                tid);  // A0(0)
    stage_ht(W, ldw, n0,       kz,      Bs0,                tid);  // B0(0)
    stage_ht(A, lda, m0 + 128, kz,      As0 + 8192,         tid);  // A1(0)
    stage_ht(W, ldw, n0 + 128, kz,      Bs0 + 8192,         tid);  // B1(0)
    stage_ht(A, lda, m0,       kz + 64, As0 + 16384,        tid);  // A0(1)
    stage_ht(W, ldw, n0 + 128, kz + 64, Bs0 + 16384 + 8192, tid);  // B1(1)
    asm volatile("s_waitcnt vmcnt(4)" ::: "memory");   // tile0 landed
    __builtin_amdgcn_sched_barrier(0);
    __builtin_amdgcn_s_barrier();

    for (int t = 0; t < NT; ++t) {
        const int cur = t & 1;
        const unsigned short* dA = As0 + cur * 16384;
        const unsigned short* dB = Bs0 + cur * 16384;
        unsigned short* Anx = As0 + (cur ^ 1) * 16384;
        unsigned short* Bnx = Bs0 + (cur ^ 1) * 16384;
        unsigned short* Acu = As0 + cur * 16384;
        unsigned short* Bcu = Bs0 + cur * 16384;
        const int k1 = kz + (t + 1) * 64, k2 = kz + (t + 2) * 64;
        const bool s1 = (t + 1 < NT), s2 = (t + 2 < NT);

        PHASE(0, 0, { if (s1) stage_ht(W, ldw, n0,       k1, Bnx,        tid); })
        __builtin_amdgcn_s_barrier();
        PHASE(0, 1, { if (s1) stage_ht(A, lda, m0 + 128, k1, Anx + 8192, tid); })
        __builtin_amdgcn_s_barrier();
        PHASE(1, 1, { if (s2) stage_ht(A, lda, m0,       k2, Acu,        tid); })   // A0 dead after ph1
        __builtin_amdgcn_s_barrier();
        PHASE(1, 0, { if (s2) stage_ht(W, ldw, n0 + 128, k2, Bcu + 8192, tid); })   // B1 dead after ph2
        if (s2) { asm volatile("s_waitcnt vmcnt(4)" ::: "memory"); }  // tile t+1 landed, t+2 in flight
        else    { asm volatile("s_waitcnt vmcnt(0)" ::: "memory"); }  // tail drain
        __builtin_amdgcn_sched_barrier(0);
        __builtin_amdgcn_s_barrier();
    }

    // ---- epilogue ----
    const int rb = m0 + wm16 + quad * 4;
    const int cb = wn16 + col;
    if (MODE == 0) {
        const int sel = n0 >> 10;
        unsigned short* Cb = sel == 0 ? C0 : sel == 1 ? C1 : C2;
        const float* bs = sel == 0 ? bias0 : sel == 1 ? bias1 : bias2;
        const int nb = (n0 & 1023) + cb;
        float bv[4];
        #pragma unroll
        for (int nt = 0; nt < 4; ++nt) bv[nt] = bs[nb + nt * 64];
        #pragma unroll
        for (int mt = 0; mt < 8; ++mt)
            #pragma unroll
            for (int rg = 0; rg < 4; ++rg) {
                const size_t ro = (size_t)(rb + mt * 32 + rg) * 1024 + nb;
                #pragma unroll
                for (int nt = 0; nt < 4; ++nt)
                    Cb[ro + nt * 64] = f2b(acc[mt][nt][rg] + bv[nt]);
            }
    } else if (MODE == 1) {
        float bv[4];
        #pragma unroll
        for (int nt = 0; nt < 4; ++nt) bv[nt] = bias0[n0 + cb + nt * 64];
        #pragma unroll
        for (int mt = 0; mt < 8; ++mt)
            #pragma unroll
            for (int rg = 0; rg < 4; ++rg) {
                const size_t ro = (size_t)(rb + mt * 32 + rg) * 4096 + n0 + cb;
                #pragma unroll
                for (int nt = 0; nt < 4; ++nt)
                    C0[ro + nt * 64] = f2b(fmaxf(acc[mt][nt][rg] + bv[nt], 0.f));
            }
    } else {
        unsigned short* Cb = blockIdx.z ? C1 : C0;
        const bool z0 = (blockIdx.z == 0);
        float bv[4];
        #pragma unroll
        for (int nt = 0; nt < 4; ++nt) bv[nt] = z0 ? bias0[n0 + cb + nt * 64] : 0.f;
        #pragma unroll
        for (int mt = 0; mt < 8; ++mt)
            #pragma unroll
            for (int rg = 0; rg < 4; ++rg) {
                const size_t ro = (size_t)(rb + mt * 32 + rg) * 1024 + n0 + cb;
                #pragma unroll
                for (int nt = 0; nt < 4; ++nt) {
                    float c = acc[mt][nt][rg] + bv[nt];
                    if (z0) c += bits2f(res[ro + nt * 64]);
                    Cb[ro + nt * 64] = f2b(c);
                }
            }
    }
}

// ---------------- V transpose: vb bf16 [4096][1024] -> vt bf16 [bp][d][j] ----------------
__global__ __launch_bounds__(256)
void vtrans_kernel(const unsigned short* __restrict__ v, unsigned short* __restrict__ vt)
{
    __shared__ unsigned short t[64][68];
    const int bpmm = blockIdx.x;
    const int bp = bpmm >> 6, mm = bpmm & 63;
    const unsigned short* vr = v + (size_t)(bp * 64 + mm) * 1024;
    const int tid = threadIdx.x;
    #pragma unroll
    for (int it = 0; it < 4; ++it) {
        int c = (tid >> 6) + it * 4;
        int d = tid & 63;
        t[d][c] = vr[c * 64 + d];
    }
    __syncthreads();
    int d = tid >> 2, qq = tid & 3;
    ushort4 o = { t[d][qq * 4 + 0], t[d][qq * 4 + 1], t[d][qq * 4 + 2], t[d][qq * 4 + 3] };
    *(ushort4*)(vt + (size_t)bp * 65536 + (size_t)d * 1024 + mm * 16 + qq * 4) = o;
}

// ---------------- MFMA attention v3 (unchanged, proven) ----------------
__global__ __launch_bounds__(256, 2)
void attn_mfma_kernel(const unsigned short* __restrict__ qb,
                      const unsigned short* __restrict__ kb,
                      const unsigned short* __restrict__ vt,
                      const unsigned short* __restrict__ rbias,
                      const int* __restrict__ pmask,
                      unsigned short* __restrict__ att)
{
    __shared__ unsigned short Qs[128 * 64];
    __shared__ unsigned short KP[128 * 64];
    __shared__ unsigned short Vt[64 * 128];
    __shared__ unsigned short rbs[2048];
    __shared__ unsigned short pmls[1024];

    const int tid = threadIdx.x;
    const int w = tid >> 6, lane = tid & 63;
    const int quad = lane >> 4, col = lane & 15;
    const int bp = blockIdx.x, i0 = blockIdx.y * 128;
    const int h = bp & 15, bb = bp >> 4;
    const size_t base = (size_t)bp << 16;
    const int myrow0 = w * 32, myrow1 = w * 32 + 16;

    {
        const unsigned short* qg = qb + base + (size_t)i0 * 64;
        #pragma unroll
        for (int it = 0; it < 4; ++it) {
            int idx = it * 256 + tid;
            int r = idx >> 3, c = idx & 7;
            s8v d = *(const s8v*)(qg + (size_t)r * 64 + (c ^ (r & 7)) * 8);
            *(s8v*)(Qs + r * 64 + c * 8) = d;
        }
    }
    {
        const unsigned short* rg = rbias + h * 2048;
        #pragma unroll
        for (int it = 0; it < 8; ++it) rbs[it * 256 + tid] = rg[it * 256 + tid];
    }
    #pragma unroll
    for (int it = 0; it < 4; ++it) {
        int j = it * 256 + tid;
        pmls[j] = f2b(__logf((float)pmask[bb * 1024 + j]));
    }

    f32x4 O0[4] = {}, O1[4] = {};
    float lrow0[4] = {0.f, 0.f, 0.f, 0.f};
    float lrow1[4] = {0.f, 0.f, 0.f, 0.f};

    unsigned short* Pw = KP + w * 2048;

    for (int jt = 0; jt < 8; ++jt) {
        const int j0 = jt * 128;
        __syncthreads();
        {
            const unsigned short* kg = kb + base + (size_t)j0 * 64;
            #pragma unroll
            for (int it = 0; it < 4; ++it) {
                int idx = it * 256 + tid;
                int r = idx >> 3, c = idx & 7;
                s8v d = *(const s8v*)(kg + (size_t)r * 64 + (c ^ (r & 7)) * 8);
                *(s8v*)(KP + r * 64 + c * 8) = d;
            }
            const unsigned short* vg = vt + base + j0;
            #pragma unroll
            for (int it = 0; it < 4; ++it) {
                int idx = it * 256 + tid;
                int r = idx >> 4, c = idx & 15;
                s8v d = *(const s8v*)(vg + (size_t)r * 1024 + (c ^ (r & 15)) * 8);
                *(s8v*)(Vt + r * 128 + c * 8) = d;
            }
        }
        __syncthreads();

        f32x4 S0[8] = {}, S1[8] = {};
        #pragma unroll
        for (int ks = 0; ks < 2; ++ks) {
            int ar0 = myrow0 + col, ar1 = myrow1 + col;
            s8v a0 = *(const s8v*)(Qs + ar0 * 64 + (((ks * 4 + quad) ^ (ar0 & 7)) * 8));
            s8v a1 = *(const s8v*)(Qs + ar1 * 64 + (((ks * 4 + quad) ^ (ar1 & 7)) * 8));
            #pragma unroll
            for (int ct = 0; ct < 8; ++ct) {
                int br = ct * 16 + col;
                s8v b = *(const s8v*)(KP + br * 64 + (((ks * 4 + quad) ^ (br & 7)) * 8));
                S0[ct] = __builtin_amdgcn_mfma_f32_16x16x32_bf16(a0, b, S0[ct], 0, 0, 0);
                S1[ct] = __builtin_amdgcn_mfma_f32_16x16x32_bf16(a1, b, S1[ct], 0, 0, 0);
            }
        }

        #pragma unroll
        for (int ct = 0; ct < 8; ++ct) {
            int gj = j0 + ct * 16 + col;
            float pmv = bits2f(pmls[gj]);
            int d0 = gj - (i0 + myrow0 + quad * 4) + 1023;
            int d1 = gj - (i0 + myrow1 + quad * 4) + 1023;
            #pragma unroll
            for (int r = 0; r < 4; ++r) {
                float e0 = __expf(S0[ct][r] + bits2f(rbs[d0 - r]) + pmv);
                float e1 = __expf(S1[ct][r] + bits2f(rbs[d1 - r]) + pmv);
                S0[ct][r] = e0; lrow0[r] += e0;
                S1[ct][r] = e1; lrow1[r] += e1;
            }
        }

        __syncthreads();

        #pragma unroll
        for (int ct = 0; ct < 8; ++ct)
            #pragma unroll
            for (int r = 0; r < 4; ++r) {
                int lr = quad * 4 + r;
                int j = ct * 16 + col;
                Pw[lr * 128 + (((j >> 3) ^ lr) << 3) + (j & 7)] = f2b(S0[ct][r]);
            }
        #pragma unroll
        for (int kt = 0; kt < 4; ++kt) {
            int pr = col;
            s8v a = *(const s8v*)(Pw + pr * 128 + (((kt * 4 + quad) ^ pr) * 8));
            #pragma unroll
            for (int nt = 0; nt < 4; ++nt) {
                int vr = nt * 16 + col;
                s8v b = *(const s8v*)(Vt + vr * 128 + (((kt * 4 + quad) ^ (vr & 15)) * 8));
                O0[nt] = __builtin_amdgcn_mfma_f32_16x16x32_bf16(a, b, O0[nt], 0, 0, 0);
            }
        }

        #pragma unroll
        for (int ct = 0; ct < 8; ++ct)
            #pragma unroll
            for (int r = 0; r < 4; ++r) {
                int lr = quad * 4 + r;
                int j = ct * 16 + col;
                Pw[lr * 128 + (((j >> 3) ^ lr) << 3) + (j & 7)] = f2b(S1[ct][r]);
            }
        #pragma unroll
        for (int kt = 0; kt < 4; ++kt) {
            int pr = col;
            s8v a = *(const s8v*)(Pw + pr * 128 + (((kt * 4 + quad) ^ pr) * 8));
            #pragma unroll
            for (int nt = 0; nt < 4; ++nt) {
                int vr = nt * 16 + col;
                s8v b = *(const s8v*)(Vt + vr * 128 + (((kt * 4 + quad) ^ (vr & 15)) * 8));
                O1[nt] = __builtin_amdgcn_mfma_f32_16x16x32_bf16(a, b, O1[nt], 0, 0, 0);
            }
        }
    }

    #pragma unroll
    for (int off = 1; off < 16; off <<= 1)
        #pragma unroll
        for (int r = 0; r < 4; ++r) {
            lrow0[r] += __shfl_xor(lrow0[r], off);
            lrow1[r] += __shfl_xor(lrow1[r], off);
        }
    #pragma unroll
    for (int r = 0; r < 4; ++r) {
        lrow0[r] = 1.f / lrow0[r];
        lrow1[r] = 1.f / lrow1[r];
    }

    unsigned short* ag0 = att + base + (size_t)(i0 + myrow0) * 64;
    unsigned short* ag1 = att + base + (size_t)(i0 + myrow1) * 64;
    #pragma unroll
    for (int nt = 0; nt < 4; ++nt)
        #pragma unroll
        for (int r = 0; r < 4; ++r) {
            ag0[(size_t)(quad * 4 + r) * 64 + nt * 16 + col] = f2b(O0[nt][r] * lrow0[r]);
            ag1[(size_t)(quad * 4 + r) * 64 + nt * 16 + col] = f2b(O1[nt][r] * lrow1[r]);
        }
}

// ---------------- layernorm over rows of 1024: in1+in2 -> (outF fp32, outB bf16) ----------------
template<typename TIN>
__global__ __launch_bounds__(256)
void ln_kernel(const TIN* __restrict__ in1, const TIN* __restrict__ in2,
               float* __restrict__ outF, unsigned short* __restrict__ outB)
{
    __shared__ float sred[8];
    const int row = blockIdx.x;
    const int tid = threadIdx.x;
    const size_t off = (size_t)row * 1024 + tid * 4;
    float a[4];
    load4(in1 + off, a);
    if (in2) {
        float b[4];
        load4(in2 + off, b);
        #pragma unroll
        for (int i = 0; i < 4; ++i) a[i] += b[i];
    }

    float lsum = a[0] + a[1] + a[2] + a[3];
    #pragma unroll
    for (int o = 32; o; o >>= 1) lsum += __shfl_down(lsum, o);
    const int lane = tid & 63, wid = tid >> 6;
    if (lane == 0) sred[wid] = lsum;
    __syncthreads();
    if (tid == 0) sred[4] = (sred[0] + sred[1] + sred[2] + sred[3]) * (1.f / 1024.f);
    __syncthreads();
    const float mean = sred[4];

    float d0 = a[0] - mean, d1 = a[1] - mean, d2 = a[2] - mean, d3 = a[3] - mean;
    float lsq = d0 * d0 + d1 * d1 + d2 * d2 + d3 * d3;
    #pragma unroll
    for (int o = 32; o; o >>= 1) lsq += __shfl_down(lsq, o);
    __syncthreads();
    if (lane == 0) sred[wid] = lsq;
    __syncthreads();
    if (tid == 0) sred[5] = rsqrtf((sred[0] + sred[1] + sred[2] + sred[3]) * (1.f / 1024.f));
    __syncthreads();
    const float r = sred[5];

    float o0 = d0 * r, o1 = d1 * r, o2 = d2 * r, o3 = d3 * r;
    if (outF) {
        float4 o = {o0, o1, o2, o3};
        *(float4*)&outF[off] = o;
    }
    if (outB) {
        ushort4 o = { f2b(o0), f2b(o1), f2b(o2), f2b(o3) };
        *(ushort4*)&outB[off] = o;
    }
}

extern "C" void kernel_launch(void* const* d_in, const int* in_sizes, int n_in,
                              void* d_out, int out_size, void* d_ws, size_t ws_size,
                              hipStream_t stream)
{
    const float* x     = (const float*)d_in[0];
    const int*   pmask = (const int*)  d_in[1];
    const float* Wq    = (const float*)d_in[2];
    const float* bq    = (const float*)d_in[3];
    const float* Wk    = (const float*)d_in[4];
    const float* bk    = (const float*)d_in[5];
    const float* Wv    = (const float*)d_in[6];
    const float* bv    = (const float*)d_in[7];
    const float* Wo    = (const float*)d_in[8];
    const float* bo    = (const float*)d_in[9];
    const float* rel   = (const float*)d_in[10];
    const float* W1    = (const float*)d_in[11];
    const float* b1    = (const float*)d_in[12];
    const float* W2    = (const float*)d_in[13];
    const float* b2    = (const float*)d_in[14];

    const int M = 4096, D = 1024;
    dim3 blk(256);

    // ---- workspace map (unchanged) ----
    char* ws = (char*)d_ws;
    unsigned short* W1b   = (unsigned short*)(ws);                 // 0-8
    unsigned short* W2b   = (unsigned short*)(ws + ( 8u << 20));   // 8-16
    unsigned short* xb    = (unsigned short*)(ws + (16u << 20));   // 16-24
    unsigned short* Wqkvb = (unsigned short*)(ws + (24u << 20));   // 24-30
    unsigned short* Wob   = (unsigned short*)(ws + (30u << 20));   // 30-32
    unsigned short* qb    = (unsigned short*)(ws + (32u << 20));   // 32-40
    unsigned short* kb    = (unsigned short*)(ws + (40u << 20));   // 40-48
    unsigned short* vb    = (unsigned short*)(ws + (48u << 20));   // 48-56
    unsigned short* vt    = (unsigned short*)(ws + (56u << 20));   // 56-64
    unsigned short* rbias = (unsigned short*)(ws + (64u << 20));   // 64-64.0625
    float*          tmpA    = (float*)(ws + (32u << 20));          // 32-48
    float*          tmpB    = (float*)(ws + (48u << 20));          // 48-64
    unsigned short* attoutB = (unsigned short*)(ws + (16u << 20)); // 16-24
    unsigned short* ff1     = (unsigned short*)(ws + (32u << 20)); // 32-64
    unsigned short* ff2a    = (unsigned short*)(ws);               // 0-8
    unsigned short* ff2b    = (unsigned short*)(ws + (24u << 20)); // 24-32
    unsigned short* attb    = (unsigned short*)d_out;              // d_out scratch

    // 128KB dynamic LDS opt-in (once per process; host-side, capture-safe)
    static bool attrset = false;
    if (!attrset) {
        hipFuncSetAttribute(reinterpret_cast<const void*>(gemm256<0>),
                            hipFuncAttributeMaxDynamicSharedMemorySize, 131072);
        hipFuncSetAttribute(reinterpret_cast<const void*>(gemm256<1>),
                            hipFuncAttributeMaxDynamicSharedMemorySize, 131072);
        hipFuncSetAttribute(reinterpret_cast<const void*>(gemm256<2>),
                            hipFuncAttributeMaxDynamicSharedMemorySize, 131072);
        attrset = true;
    }

    // ---- conversions / tables ----
    cvt_all_kernel<<<16384, blk, 0, stream>>>(x, Wq, Wk, Wv, Wo, W1, W2,
                                              xb, Wqkvb, Wob, W1b, W2b);
    rbias_kernel<<<128, blk, 0, stream>>>(rel, rbias);

    // ---- fused QKV projection: 256^2 8-phase, N=3072 routed to qb/kb/vb ----
    gemm256<0><<<dim3(12, 16), dim3(512), 131072, stream>>>(
        xb, D, Wqkvb, D, bq, bk, bv, nullptr, qb, kb, vb, 16, 0);

    vtrans_kernel<<<4096, blk, 0, stream>>>(vb, vt);

    // ---- attention v3 (unchanged) ----
    attn_mfma_kernel<<<dim3(64, 8), blk, 0, stream>>>(qb, kb, vt, rbias, pmask, attb);

    // ---- Wo projection + residual x (legacy kernel), split-K z=2 -> fp32; LN1 ----
    mfma_gemm<float, float, 0, 0><<<dim3(8, 32, 2), blk, 0, stream>>>(
        attb, D, Wob, D, bo, nullptr, nullptr, x, tmpA, tmpB, nullptr, D, M, D, 512);
    ln_kernel<float><<<4096, blk, 0, stream>>>(tmpA, tmpB, nullptr, attoutB);

    // ---- FFN: ff1 256^2 8-phase N=4096; ff2 256^2 8-phase split-K z=2; LN2 sums ----
    gemm256<1><<<dim3(16, 16), dim3(512), 131072, stream>>>(
        attoutB, D, W1b, D, b1, nullptr, nullptr, nullptr, ff1, nullptr, nullptr, 16, 0);
    gemm256<2><<<dim3(4, 16, 2), dim3(512), 131072, stream>>>(
        ff1, 4096, W2b, 4096, b2, nullptr, nullptr, attoutB, ff2a, ff2b, nullptr, 32, 2048);
    ln_kernel<unsigned short><<<4096, blk, 0, stream>>>(ff2a, ff2b, (float*)d_out, nullptr);
}

// Round 3
// 420.152 us; speedup vs baseline: 1.1022x; 1.1022x over previous
//
#include <hip/hip_runtime.h>
#include <hip/hip_bf16.h>

typedef __hip_bfloat16 bf16;
typedef __attribute__((ext_vector_type(8))) short s8v;      // 8 bf16 (4 VGPRs) MFMA A/B frag
typedef __attribute__((ext_vector_type(4))) float f32x4;    // MFMA C/D frag

__device__ __forceinline__ float bits2f(unsigned short u) {
    return __uint_as_float(((unsigned)u) << 16);
}
__device__ __forceinline__ unsigned short f2b(float f) {   // fp32 -> bf16 RNE
    union { float f; unsigned u; } x{f};
    return (unsigned short)((x.u + 0x7fff + ((x.u >> 16) & 1)) >> 16);
}
__device__ __forceinline__ float to_f(float x) { return x; }
__device__ __forceinline__ float to_f(unsigned short x) { return bits2f(x); }

__device__ __forceinline__ void load4(const float* p, float* a) {
    float4 t = *(const float4*)p;
    a[0] = t.x; a[1] = t.y; a[2] = t.z; a[3] = t.w;
}
__device__ __forceinline__ void load4(const unsigned short* p, float* a) {
    ushort4 t = *(const ushort4*)p;
    a[0] = bits2f(t.x); a[1] = bits2f(t.y); a[2] = bits2f(t.z); a[3] = bits2f(t.w);
}

// ---------------- fused fp32 -> bf16 convert of x + all weights ----------------
__global__ __launch_bounds__(256)
void cvt_all_kernel(const float* __restrict__ x,
                    const float* __restrict__ Wq, const float* __restrict__ Wk,
                    const float* __restrict__ Wv, const float* __restrict__ Wo,
                    const float* __restrict__ W1, const float* __restrict__ W2,
                    unsigned short* __restrict__ xb, unsigned short* __restrict__ Wqkvb,
                    unsigned short* __restrict__ Wob,
                    unsigned short* __restrict__ W1b, unsigned short* __restrict__ W2b)
{
    int i = blockIdx.x * 256 + threadIdx.x;
    const float* src; unsigned short* dst; int off;
    if (i < (1 << 20))      { src = x;  dst = xb;  off = i; }
    else if (i < (2 << 20)) { src = W1; dst = W1b; off = i - (1 << 20); }
    else if (i < (3 << 20)) { src = W2; dst = W2b; off = i - (2 << 20); }
    else {
        int j = i - (3 << 20);
        int sel = j >> 18;
        off = j & ((1 << 18) - 1);
        src = sel == 0 ? Wq : sel == 1 ? Wk : sel == 2 ? Wv : Wo;
        dst = sel == 3 ? Wob : Wqkvb + ((size_t)sel << 20);
    }
    float4 v = ((const float4*)src)[off];
    ushort4 o = { f2b(v.x), f2b(v.y), f2b(v.z), f2b(v.w) };
    ((ushort4*)dst)[off] = o;
}

// ---------------- per-head relative-position bias by delta (T5 buckets, double math) ----------------
__global__ void rbias_kernel(const float* __restrict__ rel_emb, unsigned short* __restrict__ rbias)
{
    int idx = blockIdx.x * 256 + threadIdx.x;   // 16 * 2048
    if (idx >= 16 * 2048) return;
    int h = idx >> 11, q = idx & 2047;
    int n = q - 1023, ret = 0;                  // n = j - i
    if (n < 0) { ret = 16; n = -n; }
    int b;
    if (n < 8) b = n;
    else {
        double t = log((double)n / 8.0) / log(16.0) * 8.0;
        int v = 8 + (int)t;
        b = v < 15 ? v : 15;
    }
    rbias[idx] = f2b(rel_emb[(ret + b) * 16 + h]);
}

// ---------------- legacy MFMA GEMM (kept for Wo projection only) ----------------
template<typename TC, typename TR, int RELU, int QKV>
__global__ __launch_bounds__(256)
void mfma_gemm(const unsigned short* __restrict__ A, int lda,
               const unsigned short* __restrict__ W, int ldw,
               const float* __restrict__ b0, const float* __restrict__ b1,
               const float* __restrict__ b2,
               const TR* __restrict__ res,
               void* __restrict__ C0, void* __restrict__ C1, void* __restrict__ C2,
               int ldc, int M, int N, int Ksplit)
{
    __shared__ unsigned short sm[2 * 128 * 32];
    unsigned short* As = sm;
    unsigned short* Ws = sm + 128 * 32;

    const int tid = threadIdx.x;
    const int w = tid >> 6, lane = tid & 63;
    const int quad = lane >> 4, col = lane & 15;
    const int m0 = blockIdx.y * 128, n0 = blockIdx.x * 128;
    const int wrow = (w & 1) * 64, wcol = (w >> 1) * 64;
    const int kz = blockIdx.z * Ksplit;

    const int srow   = lane >> 2;
    const int schunk = (lane & 3) ^ ((lane >> 4) & 3);

    f32x4 acc[4][4] = {};

    for (int k0 = kz; k0 < kz + Ksplit; k0 += 32) {
        __syncthreads();
        #pragma unroll
        for (int t = 0; t < 2; ++t) {
            const int rbase = w * 32 + t * 16;
            unsigned off = (unsigned)(rbase * 64);
            off = __builtin_amdgcn_readfirstlane(off);
            const unsigned short* ga = A + (size_t)(m0 + rbase + srow) * lda + k0 + schunk * 8;
            __builtin_amdgcn_global_load_lds(
                (const __attribute__((address_space(1))) unsigned int*)ga,
                (__attribute__((address_space(3))) unsigned int*)((char*)As + off), 16, 0, 0);
            const unsigned short* gw = W + (size_t)(n0 + rbase + srow) * ldw + k0 + schunk * 8;
            __builtin_amdgcn_global_load_lds(
                (const __attribute__((address_space(1))) unsigned int*)gw,
                (__attribute__((address_space(3))) unsigned int*)((char*)Ws + off), 16, 0, 0);
        }
        __syncthreads();

        s8v af[4], bfr[4];
        #pragma unroll
        for (int mt = 0; mt < 4; ++mt) {
            int rr = wrow + mt * 16 + col;
            af[mt] = *(const s8v*)(As + rr * 32 + ((quad ^ ((rr >> 2) & 3)) * 8));
        }
        #pragma unroll
        for (int nt = 0; nt < 4; ++nt) {
            int rr = wcol + nt * 16 + col;
            bfr[nt] = *(const s8v*)(Ws + rr * 32 + ((quad ^ ((rr >> 2) & 3)) * 8));
        }
        #pragma unroll
        for (int mt = 0; mt < 4; ++mt)
            #pragma unroll
            for (int nt = 0; nt < 4; ++nt)
                acc[mt][nt] = __builtin_amdgcn_mfma_f32_16x16x32_bf16(af[mt], bfr[nt], acc[mt][nt], 0, 0, 0);
    }

    if (QKV) {
        const int sel = n0 >> 10;
        unsigned short* Cb = (unsigned short*)(sel == 0 ? C0 : sel == 1 ? C1 : C2);
        const float* bs = sel == 0 ? b0 : sel == 1 ? b1 : b2;
        #pragma unroll
        for (int mt = 0; mt < 4; ++mt)
            #pragma unroll
            for (int rg = 0; rg < 4; ++rg) {
                int gm = m0 + wrow + mt * 16 + quad * 4 + rg;
                #pragma unroll
                for (int nt = 0; nt < 4; ++nt) {
                    int gnc = (n0 + wcol + nt * 16 + col) & 1023;
                    Cb[(size_t)gm * 1024 + gnc] = f2b(acc[mt][nt][rg] + bs[gnc]);
                }
            }
    } else {
        void* Cv = blockIdx.z ? C1 : C0;
        const bool z0 = (blockIdx.z == 0);
        #pragma unroll
        for (int mt = 0; mt < 4; ++mt)
            #pragma unroll
            for (int rg = 0; rg < 4; ++rg) {
                int gm = m0 + wrow + mt * 16 + quad * 4 + rg;
                #pragma unroll
                for (int nt = 0; nt < 4; ++nt) {
                    int gn = n0 + wcol + nt * 16 + col;
                    float c = acc[mt][nt][rg];
                    if (z0) {
                        if (b0)  c += b0[gn];
                        if (res) c += to_f(res[(size_t)gm * ldc + gn]);
                    }
                    if (RELU) c = fmaxf(c, 0.f);
                    if (sizeof(TC) == 2) ((unsigned short*)Cv)[(size_t)gm * ldc + gn] = f2b(c);
                    else                 ((float*)Cv)[(size_t)gm * ldc + gn] = c;
                }
            }
    }
}

// ================= 256x256 8-phase counted-vmcnt GEMM, v2 (resubmit) =================
// v2 repairs vs v1: (a) NO sched_barrier/lgkmcnt pinning (m141 lesson) — compiler
// schedules ds_read∥MFMA with counted lgkm waits; (b) operand reuse, phase order
// (0,0)(1,0)(1,1)(0,1): 32 ds_read_b128/K-tile instead of 48; (c) swizzle
// chunk ^= (row&7): 2-way max residual conflict; (d) vmcnt(8) mid-tile +
// vmcnt(6) at boundary, 3 half-tiles in flight, never 0 until the tail.
//
// Stage schedule (region-liveness proven):
//   ph0 reads A0,B0 : stage A0(t+1) -> next buf
//   ph1 reads A1,(B0): stage B1(t+1) -> next buf     [then vmcnt(8): B1(t) landed]
//   ph2 reads (A1),B1: stage B0(t+2) -> cur (B0 dead after ph0 reads)
//   ph3 reads A0,(B1): stage A1(t+2) -> cur (A1 dead after ph1 reads)
//                                                    [then vmcnt(6): tile t+1 A0/B0/A1 landed]
// In-flight invariant entering tile t: {B1(t), B0(t+1), A1(t+1)} = 6 loads.

__device__ __forceinline__ void stage_ht(const unsigned short* __restrict__ g, int ld,
                                         int grow0, int kbase,
                                         unsigned short* lds_half, int tid)
{
    // one 128x64 bf16 half-tile: 2 x global_load_lds(16B)/thread, linear LDS dest;
    // global source pre-swizzled (chunk ^ (row&7)) so swizzled ds_reads match (rule 21).
    #pragma unroll
    for (int l = 0; l < 2; ++l) {
        int idx = l * 512 + tid;
        int r = idx >> 3;
        int c = (idx & 7) ^ (r & 7);
        const unsigned short* src = g + (size_t)(grow0 + r) * ld + kbase + c * 8;
        unsigned off = (unsigned)__builtin_amdgcn_readfirstlane((unsigned)((l * 512 + (tid & 448)) * 16));
        __builtin_amdgcn_global_load_lds(
            (const __attribute__((address_space(1))) unsigned int*)src,
            (__attribute__((address_space(3))) unsigned int*)((char*)lds_half + off), 16, 0, 0);
    }
}

#define LDA(HM)                                                                   \
    _Pragma("unroll")                                                             \
    for (int mt2 = 0; mt2 < 4; ++mt2) {                                           \
        int r = ((HM) * 4 + mt2) * 32 + wm16 + col;                               \
        _Pragma("unroll")                                                         \
        for (int ks = 0; ks < 2; ++ks)                                            \
            aA[mt2][ks] = *(const s8v*)(dA + r * 64 + (((ks * 4 + quad) ^ (r & 7)) << 3)); \
    }

#define LDB(HN)                                                                   \
    _Pragma("unroll")                                                             \
    for (int nt2 = 0; nt2 < 2; ++nt2) {                                           \
        int r = ((HN) * 2 + nt2) * 64 + wn16 + col;                               \
        _Pragma("unroll")                                                         \
        for (int ks = 0; ks < 2; ++ks)                                            \
            bB[nt2][ks] = *(const s8v*)(dB + r * 64 + (((ks * 4 + quad) ^ (r & 7)) << 3)); \
    }

#define MFMAQ(HM, HN)                                                             \
    __builtin_amdgcn_s_setprio(1);                                                \
    _Pragma("unroll")                                                             \
    for (int ks = 0; ks < 2; ++ks)                                                \
        _Pragma("unroll")                                                         \
        for (int mt2 = 0; mt2 < 4; ++mt2)                                         \
            _Pragma("unroll")                                                     \
            for (int nt2 = 0; nt2 < 2; ++nt2)                                     \
                acc[(HM) * 4 + mt2][(HN) * 2 + nt2] =                             \
                    __builtin_amdgcn_mfma_f32_16x16x32_bf16(                      \
                        aA[mt2][ks], bB[nt2][ks], acc[(HM) * 4 + mt2][(HN) * 2 + nt2], 0, 0, 0); \
    __builtin_amdgcn_s_setprio(0);

// MODE 0: QKV route by n-segment (bias bq/bk/bv, bf16 out ldc=1024)
// MODE 1: ff1 bias+relu, bf16 out ldc=4096
// MODE 2: ff2 split-K z: z0 adds bias+bf16 residual; bf16 partial out ldc=1024
template<int MODE>
__global__ __launch_bounds__(512, 2)
void gemm256(const unsigned short* __restrict__ A, int lda,
             const unsigned short* __restrict__ W, int ldw,
             const float* __restrict__ bias0, const float* __restrict__ bias1,
             const float* __restrict__ bias2,
             const unsigned short* __restrict__ res,
             unsigned short* __restrict__ C0, unsigned short* __restrict__ C1,
             unsigned short* __restrict__ C2,
             int NT, int Ksplit)
{
    extern __shared__ unsigned short sm[];
    unsigned short* As0 = sm;            // [2][256*64]  (A0 half, A1 half per buf)
    unsigned short* Bs0 = sm + 32768;    // [2][256*64]

    const int tid = threadIdx.x;
    const int w = tid >> 6, lane = tid & 63;
    const int quad = lane >> 4, col = lane & 15;
    const int wm16 = (w & 1) * 16, wn16 = (w >> 1) * 16;

    // XCD-bijective swizzle (nwg % 8 == 0 for all launches here)
    const int bid = blockIdx.x + gridDim.x * blockIdx.y;
    const int nwg = gridDim.x * gridDim.y;
    const int swz = (bid & 7) * (nwg >> 3) + (bid >> 3);
    const int m0 = (swz / gridDim.x) * 256;
    const int n0 = (swz % gridDim.x) * 256;
    const int kz = blockIdx.z * Ksplit;

    f32x4 acc[8][4] = {};

    // prologue: issue order matches steady-state age invariant
    stage_ht(W, ldw, n0,       kz,      Bs0,                tid);  // B0(0)
    stage_ht(A, lda, m0 + 128, kz,      As0 + 8192,         tid);  // A1(0)
    stage_ht(A, lda, m0,       kz,      As0,                tid);  // A0(0)
    stage_ht(W, ldw, n0 + 128, kz,      Bs0 + 8192,         tid);  // B1(0)
    stage_ht(W, ldw, n0,       kz + 64, Bs0 + 16384,        tid);  // B0(1)
    stage_ht(A, lda, m0 + 128, kz + 64, As0 + 16384 + 8192, tid);  // A1(1)
    asm volatile("s_waitcnt vmcnt(6)" ::: "memory");   // B0(0),A1(0),A0(0) landed
    __builtin_amdgcn_s_barrier();

    for (int t = 0; t < NT; ++t) {
        const int cur = t & 1;
        const unsigned short* dA = As0 + cur * 16384;
        const unsigned short* dB = Bs0 + cur * 16384;
        unsigned short* nA = As0 + (cur ^ 1) * 16384;
        unsigned short* nB = Bs0 + (cur ^ 1) * 16384;
        unsigned short* cA = (unsigned short*)dA;
        unsigned short* cB = (unsigned short*)dB;
        const int k1 = kz + (t + 1) * 64, k2 = kz + (t + 2) * 64;
        const bool s1 = (t + 1 < NT), s2 = (t + 2 < NT);

        s8v aA[4][2], bB[2][2];

        // ph0: quadrant (0,0)
        LDA(0); LDB(0);
        if (s1) stage_ht(A, lda, m0, k1, nA, tid);              // A0(t+1) -> nx
        __builtin_amdgcn_s_barrier();
        MFMAQ(0, 0);
        __builtin_amdgcn_s_barrier();

        // ph1: quadrant (1,0), reuse B0
        LDA(1);
        if (s1) stage_ht(W, ldw, n0 + 128, k1, nB + 8192, tid); // B1(t+1) -> nx
        __builtin_amdgcn_s_barrier();
        MFMAQ(1, 0);
        if (s2) { asm volatile("s_waitcnt vmcnt(8)" ::: "memory"); }   // B1(t) landed
        else    { asm volatile("s_waitcnt vmcnt(0)" ::: "memory"); }
        __builtin_amdgcn_s_barrier();

        // ph2: quadrant (1,1), reuse A1
        LDB(1);
        if (s2) stage_ht(W, ldw, n0, k2, cB, tid);              // B0(t+2) -> cur (dead)
        __builtin_amdgcn_s_barrier();
        MFMAQ(1, 1);
        __builtin_amdgcn_s_barrier();

        // ph3: quadrant (0,1), reuse B1
        LDA(0);                                                 // reload A0
        if (s2) stage_ht(A, lda, m0 + 128, k2, cA + 8192, tid); // A1(t+2) -> cur (dead)
        __builtin_amdgcn_s_barrier();
        MFMAQ(0, 1);
        if (s2) { asm volatile("s_waitcnt vmcnt(6)" ::: "memory"); }   // tile t+1 A0/B0/A1 landed
        else    { asm volatile("s_waitcnt vmcnt(0)" ::: "memory"); }
        __builtin_amdgcn_s_barrier();
    }

    // ---- epilogue ----
    const int rb = m0 + wm16 + quad * 4;
    const int cb = wn16 + col;
    if (MODE == 0) {
        const int sel = n0 >> 10;
        unsigned short* Cb = sel == 0 ? C0 : sel == 1 ? C1 : C2;
        const float* bs = sel == 0 ? bias0 : sel == 1 ? bias1 : bias2;
        const int nb = (n0 & 1023) + cb;
        float bv[4];
        #pragma unroll
        for (int nt = 0; nt < 4; ++nt) bv[nt] = bs[nb + nt * 64];
        #pragma unroll
        for (int mt = 0; mt < 8; ++mt)
            #pragma unroll
            for (int rg = 0; rg < 4; ++rg) {
                const size_t ro = (size_t)(rb + mt * 32 + rg) * 1024 + nb;
                #pragma unroll
                for (int nt = 0; nt < 4; ++nt)
                    Cb[ro + nt * 64] = f2b(acc[mt][nt][rg] + bv[nt]);
            }
    } else if (MODE == 1) {
        float bv[4];
        #pragma unroll
        for (int nt = 0; nt < 4; ++nt) bv[nt] = bias0[n0 + cb + nt * 64];
        #pragma unroll
        for (int mt = 0; mt < 8; ++mt)
            #pragma unroll
            for (int rg = 0; rg < 4; ++rg) {
                const size_t ro = (size_t)(rb + mt * 32 + rg) * 4096 + n0 + cb;
                #pragma unroll
                for (int nt = 0; nt < 4; ++nt)
                    C0[ro + nt * 64] = f2b(fmaxf(acc[mt][nt][rg] + bv[nt], 0.f));
            }
    } else {
        unsigned short* Cb = blockIdx.z ? C1 : C0;
        const bool z0 = (blockIdx.z == 0);
        float bv[4];
        #pragma unroll
        for (int nt = 0; nt < 4; ++nt) bv[nt] = z0 ? bias0[n0 + cb + nt * 64] : 0.f;
        #pragma unroll
        for (int mt = 0; mt < 8; ++mt)
            #pragma unroll
            for (int rg = 0; rg < 4; ++rg) {
                const size_t ro = (size_t)(rb + mt * 32 + rg) * 1024 + n0 + cb;
                #pragma unroll
                for (int nt = 0; nt < 4; ++nt) {
                    float c = acc[mt][nt][rg] + bv[nt];
                    if (z0) c += bits2f(res[ro + nt * 64]);
                    Cb[ro + nt * 64] = f2b(c);
                }
            }
    }
}

// ---------------- V transpose: vb bf16 [4096][1024] -> vt bf16 [bp][d][j] ----------------
__global__ __launch_bounds__(256)
void vtrans_kernel(const unsigned short* __restrict__ v, unsigned short* __restrict__ vt)
{
    __shared__ unsigned short t[64][68];
    const int bpmm = blockIdx.x;
    const int bp = bpmm >> 6, mm = bpmm & 63;
    const unsigned short* vr = v + (size_t)(bp * 64 + mm) * 1024;
    const int tid = threadIdx.x;
    #pragma unroll
    for (int it = 0; it < 4; ++it) {
        int c = (tid >> 6) + it * 4;
        int d = tid & 63;
        t[d][c] = vr[c * 64 + d];
    }
    __syncthreads();
    int d = tid >> 2, qq = tid & 3;
    ushort4 o = { t[d][qq * 4 + 0], t[d][qq * 4 + 1], t[d][qq * 4 + 2], t[d][qq * 4 + 3] };
    *(ushort4*)(vt + (size_t)bp * 65536 + (size_t)d * 1024 + mm * 16 + qq * 4) = o;
}

// ---------------- MFMA attention v3 (unchanged, proven) ----------------
__global__ __launch_bounds__(256, 2)
void attn_mfma_kernel(const unsigned short* __restrict__ qb,
                      const unsigned short* __restrict__ kb,
                      const unsigned short* __restrict__ vt,
                      const unsigned short* __restrict__ rbias,
                      const int* __restrict__ pmask,
                      unsigned short* __restrict__ att)
{
    __shared__ unsigned short Qs[128 * 64];
    __shared__ unsigned short KP[128 * 64];
    __shared__ unsigned short Vt[64 * 128];
    __shared__ unsigned short rbs[2048];
    __shared__ unsigned short pmls[1024];

    const int tid = threadIdx.x;
    const int w = tid >> 6, lane = tid & 63;
    const int quad = lane >> 4, col = lane & 15;
    const int bp = blockIdx.x, i0 = blockIdx.y * 128;
    const int h = bp & 15, bb = bp >> 4;
    const size_t base = (size_t)bp << 16;
    const int myrow0 = w * 32, myrow1 = w * 32 + 16;

    {
        const unsigned short* qg = qb + base + (size_t)i0 * 64;
        #pragma unroll
        for (int it = 0; it < 4; ++it) {
            int idx = it * 256 + tid;
            int r = idx >> 3, c = idx & 7;
            s8v d = *(const s8v*)(qg + (size_t)r * 64 + (c ^ (r & 7)) * 8);
            *(s8v*)(Qs + r * 64 + c * 8) = d;
        }
    }
    {
        const unsigned short* rg = rbias + h * 2048;
        #pragma unroll
        for (int it = 0; it < 8; ++it) rbs[it * 256 + tid] = rg[it * 256 + tid];
    }
    #pragma unroll
    for (int it = 0; it < 4; ++it) {
        int j = it * 256 + tid;
        pmls[j] = f2b(__logf((float)pmask[bb * 1024 + j]));
    }

    f32x4 O0[4] = {}, O1[4] = {};
    float lrow0[4] = {0.f, 0.f, 0.f, 0.f};
    float lrow1[4] = {0.f, 0.f, 0.f, 0.f};

    unsigned short* Pw = KP + w * 2048;

    for (int jt = 0; jt < 8; ++jt) {
        const int j0 = jt * 128;
        __syncthreads();
        {
            const unsigned short* kg = kb + base + (size_t)j0 * 64;
            #pragma unroll
            for (int it = 0; it < 4; ++it) {
                int idx = it * 256 + tid;
                int r = idx >> 3, c = idx & 7;
                s8v d = *(const s8v*)(kg + (size_t)r * 64 + (c ^ (r & 7)) * 8);
                *(s8v*)(KP + r * 64 + c * 8) = d;
            }
            const unsigned short* vg = vt + base + j0;
            #pragma unroll
            for (int it = 0; it < 4; ++it) {
                int idx = it * 256 + tid;
                int r = idx >> 4, c = idx & 15;
                s8v d = *(const s8v*)(vg + (size_t)r * 1024 + (c ^ (r & 15)) * 8);
                *(s8v*)(Vt + r * 128 + c * 8) = d;
            }
        }
        __syncthreads();

        f32x4 S0[8] = {}, S1[8] = {};
        #pragma unroll
        for (int ks = 0; ks < 2; ++ks) {
            int ar0 = myrow0 + col, ar1 = myrow1 + col;
            s8v a0 = *(const s8v*)(Qs + ar0 * 64 + (((ks * 4 + quad) ^ (ar0 & 7)) * 8));
            s8v a1 = *(const s8v*)(Qs + ar1 * 64 + (((ks * 4 + quad) ^ (ar1 & 7)) * 8));
            #pragma unroll
            for (int ct = 0; ct < 8; ++ct) {
                int br = ct * 16 + col;
                s8v b = *(const s8v*)(KP + br * 64 + (((ks * 4 + quad) ^ (br & 7)) * 8));
                S0[ct] = __builtin_amdgcn_mfma_f32_16x16x32_bf16(a0, b, S0[ct], 0, 0, 0);
                S1[ct] = __builtin_amdgcn_mfma_f32_16x16x32_bf16(a1, b, S1[ct], 0, 0, 0);
            }
        }

        #pragma unroll
        for (int ct = 0; ct < 8; ++ct) {
            int gj = j0 + ct * 16 + col;
            float pmv = bits2f(pmls[gj]);
            int d0 = gj - (i0 + myrow0 + quad * 4) + 1023;
            int d1 = gj - (i0 + myrow1 + quad * 4) + 1023;
            #pragma unroll
            for (int r = 0; r < 4; ++r) {
                float e0 = __expf(S0[ct][r] + bits2f(rbs[d0 - r]) + pmv);
                float e1 = __expf(S1[ct][r] + bits2f(rbs[d1 - r]) + pmv);
                S0[ct][r] = e0; lrow0[r] += e0;
                S1[ct][r] = e1; lrow1[r] += e1;
            }
        }

        __syncthreads();

        #pragma unroll
        for (int ct = 0; ct < 8; ++ct)
            #pragma unroll
            for (int r = 0; r < 4; ++r) {
                int lr = quad * 4 + r;
                int j = ct * 16 + col;
                Pw[lr * 128 + (((j >> 3) ^ lr) << 3) + (j & 7)] = f2b(S0[ct][r]);
            }
        #pragma unroll
        for (int kt = 0; kt < 4; ++kt) {
            int pr = col;
            s8v a = *(const s8v*)(Pw + pr * 128 + (((kt * 4 + quad) ^ pr) * 8));
            #pragma unroll
            for (int nt = 0; nt < 4; ++nt) {
                int vr = nt * 16 + col;
                s8v b = *(const s8v*)(Vt + vr * 128 + (((kt * 4 + quad) ^ (vr & 15)) * 8));
                O0[nt] = __builtin_amdgcn_mfma_f32_16x16x32_bf16(a, b, O0[nt], 0, 0, 0);
            }
        }

        #pragma unroll
        for (int ct = 0; ct < 8; ++ct)
            #pragma unroll
            for (int r = 0; r < 4; ++r) {
                int lr = quad * 4 + r;
                int j = ct * 16 + col;
                Pw[lr * 128 + (((j >> 3) ^ lr) << 3) + (j & 7)] = f2b(S1[ct][r]);
            }
        #pragma unroll
        for (int kt = 0; kt < 4; ++kt) {
            int pr = col;
            s8v a = *(const s8v*)(Pw + pr * 128 + (((kt * 4 + quad) ^ pr) * 8));
            #pragma unroll
            for (int nt = 0; nt < 4; ++nt) {
                int vr = nt * 16 + col;
                s8v b = *(const s8v*)(Vt + vr * 128 + (((kt * 4 + quad) ^ (vr & 15)) * 8));
                O1[nt] = __builtin_amdgcn_mfma_f32_16x16x32_bf16(a, b, O1[nt], 0, 0, 0);
            }
        }
    }

    #pragma unroll
    for (int off = 1; off < 16; off <<= 1)
        #pragma unroll
        for (int r = 0; r < 4; ++r) {
            lrow0[r] += __shfl_xor(lrow0[r], off);
            lrow1[r] += __shfl_xor(lrow1[r], off);
        }
    #pragma unroll
    for (int r = 0; r < 4; ++r) {
        lrow0[r] = 1.f / lrow0[r];
        lrow1[r] = 1.f / lrow1[r];
    }

    unsigned short* ag0 = att + base + (size_t)(i0 + myrow0) * 64;
    unsigned short* ag1 = att + base + (size_t)(i0 + myrow1) * 64;
    #pragma unroll
    for (int nt = 0; nt < 4; ++nt)
        #pragma unroll
        for (int r = 0; r < 4; ++r) {
            ag0[(size_t)(quad * 4 + r) * 64 + nt * 16 + col] = f2b(O0[nt][r] * lrow0[r]);
            ag1[(size_t)(quad * 4 + r) * 64 + nt * 16 + col] = f2b(O1[nt][r] * lrow1[r]);
        }
}

// ---------------- layernorm over rows of 1024: in1+in2 -> (outF fp32, outB bf16) ----------------
template<typename TIN>
__global__ __launch_bounds__(256)
void ln_kernel(const TIN* __restrict__ in1, const TIN* __restrict__ in2,
               float* __restrict__ outF, unsigned short* __restrict__ outB)
{
    __shared__ float sred[8];
    const int row = blockIdx.x;
    const int tid = threadIdx.x;
    const size_t off = (size_t)row * 1024 + tid * 4;
    float a[4];
    load4(in1 + off, a);
    if (in2) {
        float b[4];
        load4(in2 + off, b);
        #pragma unroll
        for (int i = 0; i < 4; ++i) a[i] += b[i];
    }

    float lsum = a[0] + a[1] + a[2] + a[3];
    #pragma unroll
    for (int o = 32; o; o >>= 1) lsum += __shfl_down(lsum, o);
    const int lane = tid & 63, wid = tid >> 6;
    if (lane == 0) sred[wid] = lsum;
    __syncthreads();
    if (tid == 0) sred[4] = (sred[0] + sred[1] + sred[2] + sred[3]) * (1.f / 1024.f);
    __syncthreads();
    const float mean = sred[4];

    float d0 = a[0] - mean, d1 = a[1] - mean, d2 = a[2] - mean, d3 = a[3] - mean;
    float lsq = d0 * d0 + d1 * d1 + d2 * d2 + d3 * d3;
    #pragma unroll
    for (int o = 32; o; o >>= 1) lsq += __shfl_down(lsq, o);
    __syncthreads();
    if (lane == 0) sred[wid] = lsq;
    __syncthreads();
    if (tid == 0) sred[5] = rsqrtf((sred[0] + sred[1] + sred[2] + sred[3]) * (1.f / 1024.f));
    __syncthreads();
    const float r = sred[5];

    float o0 = d0 * r, o1 = d1 * r, o2 = d2 * r, o3 = d3 * r;
    if (outF) {
        float4 o = {o0, o1, o2, o3};
        *(float4*)&outF[off] = o;
    }
    if (outB) {
        ushort4 o = { f2b(o0), f2b(o1), f2b(o2), f2b(o3) };
        *(ushort4*)&outB[off] = o;
    }
}

extern "C" void kernel_launch(void* const* d_in, const int* in_sizes, int n_in,
                              void* d_out, int out_size, void* d_ws, size_t ws_size,
                              hipStream_t stream)
{
    const float* x     = (const float*)d_in[0];
    const int*   pmask = (const int*)  d_in[1];
    const float* Wq    = (const float*)d_in[2];
    const float* bq    = (const float*)d_in[3];
    const float* Wk    = (const float*)d_in[4];
    const float* bk    = (const float*)d_in[5];
    const float* Wv    = (const float*)d_in[6];
    const float* bv    = (const float*)d_in[7];
    const float* Wo    = (const float*)d_in[8];
    const float* bo    = (const float*)d_in[9];
    const float* rel   = (const float*)d_in[10];
    const float* W1    = (const float*)d_in[11];
    const float* b1    = (const float*)d_in[12];
    const float* W2    = (const float*)d_in[13];
    const float* b2    = (const float*)d_in[14];

    const int M = 4096, D = 1024;
    dim3 blk(256);

    // ---- workspace map (unchanged) ----
    char* ws = (char*)d_ws;
    unsigned short* W1b   = (unsigned short*)(ws);                 // 0-8
    unsigned short* W2b   = (unsigned short*)(ws + ( 8u << 20));   // 8-16
    unsigned short* xb    = (unsigned short*)(ws + (16u << 20));   // 16-24
    unsigned short* Wqkvb = (unsigned short*)(ws + (24u << 20));   // 24-30
    unsigned short* Wob   = (unsigned short*)(ws + (30u << 20));   // 30-32
    unsigned short* qb    = (unsigned short*)(ws + (32u << 20));   // 32-40
    unsigned short* kb    = (unsigned short*)(ws + (40u << 20));   // 40-48
    unsigned short* vb    = (unsigned short*)(ws + (48u << 20));   // 48-56
    unsigned short* vt    = (unsigned short*)(ws + (56u << 20));   // 56-64
    unsigned short* rbias = (unsigned short*)(ws + (64u << 20));   // 64-64.0625
    float*          tmpA    = (float*)(ws + (32u << 20));          // 32-48
    float*          tmpB    = (float*)(ws + (48u << 20));          // 48-64
    unsigned short* attoutB = (unsigned short*)(ws + (16u << 20)); // 16-24
    unsigned short* ff1     = (unsigned short*)(ws + (32u << 20)); // 32-64
    unsigned short* ff2a    = (unsigned short*)(ws);               // 0-8
    unsigned short* ff2b    = (unsigned short*)(ws + (24u << 20)); // 24-32
    unsigned short* attb    = (unsigned short*)d_out;              // d_out scratch

    // 128KB dynamic LDS opt-in (once per process; host-side, capture-safe)
    static bool attrset = false;
    if (!attrset) {
        hipFuncSetAttribute(reinterpret_cast<const void*>(gemm256<0>),
                            hipFuncAttributeMaxDynamicSharedMemorySize, 131072);
        hipFuncSetAttribute(reinterpret_cast<const void*>(gemm256<1>),
                            hipFuncAttributeMaxDynamicSharedMemorySize, 131072);
        hipFuncSetAttribute(reinterpret_cast<const void*>(gemm256<2>),
                            hipFuncAttributeMaxDynamicSharedMemorySize, 131072);
        attrset = true;
    }

    // ---- conversions / tables ----
    cvt_all_kernel<<<16384, blk, 0, stream>>>(x, Wq, Wk, Wv, Wo, W1, W2,
                                              xb, Wqkvb, Wob, W1b, W2b);
    rbias_kernel<<<128, blk, 0, stream>>>(rel, rbias);

    // ---- fused QKV projection: 256^2 8-phase v2, N=3072 routed to qb/kb/vb ----
    gemm256<0><<<dim3(12, 16), dim3(512), 131072, stream>>>(
        xb, D, Wqkvb, D, bq, bk, bv, nullptr, qb, kb, vb, 16, 0);

    vtrans_kernel<<<4096, blk, 0, stream>>>(vb, vt);

    // ---- attention v3 (unchanged) ----
    attn_mfma_kernel<<<dim3(64, 8), blk, 0, stream>>>(qb, kb, vt, rbias, pmask, attb);

    // ---- Wo projection + residual x (legacy kernel), split-K z=2 -> fp32; LN1 ----
    mfma_gemm<float, float, 0, 0><<<dim3(8, 32, 2), blk, 0, stream>>>(
        attb, D, Wob, D, bo, nullptr, nullptr, x, tmpA, tmpB, nullptr, D, M, D, 512);
    ln_kernel<float><<<4096, blk, 0, stream>>>(tmpA, tmpB, nullptr, attoutB);

    // ---- FFN: ff1 256^2 v2 N=4096; ff2 256^2 v2 split-K z=2; LN2 sums ----
    gemm256<1><<<dim3(16, 16), dim3(512), 131072, stream>>>(
        attoutB, D, W1b, D, b1, nullptr, nullptr, nullptr, ff1, nullptr, nullptr, 16, 0);
    gemm256<2><<<dim3(4, 16, 2), dim3(512), 131072, stream>>>(
        ff1, 4096, W2b, 4096, b2, nullptr, nullptr, attoutB, ff2a, ff2b, nullptr, 32, 2048);
    ln_kernel<unsigned short><<<4096, blk, 0, stream>>>(ff2a, ff2b, (float*)d_out, nullptr);
}

// Round 4
// 415.362 us; speedup vs baseline: 1.1149x; 1.0115x over previous
//
#include <hip/hip_runtime.h>
#include <hip/hip_bf16.h>

typedef __hip_bfloat16 bf16;
typedef __attribute__((ext_vector_type(8))) short s8v;      // 8 bf16 (4 VGPRs) MFMA A/B frag
typedef __attribute__((ext_vector_type(4))) float f32x4;    // MFMA C/D frag

__device__ __forceinline__ float bits2f(unsigned short u) {
    return __uint_as_float(((unsigned)u) << 16);
}
__device__ __forceinline__ unsigned short f2b(float f) {   // fp32 -> bf16 RNE
    union { float f; unsigned u; } x{f};
    return (unsigned short)((x.u + 0x7fff + ((x.u >> 16) & 1)) >> 16);
}
__device__ __forceinline__ float to_f(float x) { return x; }
__device__ __forceinline__ float to_f(unsigned short x) { return bits2f(x); }

__device__ __forceinline__ void load4(const float* p, float* a) {
    float4 t = *(const float4*)p;
    a[0] = t.x; a[1] = t.y; a[2] = t.z; a[3] = t.w;
}
__device__ __forceinline__ void load4(const unsigned short* p, float* a) {
    ushort4 t = *(const ushort4*)p;
    a[0] = bits2f(t.x); a[1] = bits2f(t.y); a[2] = bits2f(t.z); a[3] = bits2f(t.w);
}

// ---------------- fused fp32 -> bf16 convert of x + all weights ----------------
__global__ __launch_bounds__(256)
void cvt_all_kernel(const float* __restrict__ x,
                    const float* __restrict__ Wq, const float* __restrict__ Wk,
                    const float* __restrict__ Wv, const float* __restrict__ Wo,
                    const float* __restrict__ W1, const float* __restrict__ W2,
                    unsigned short* __restrict__ xb, unsigned short* __restrict__ Wqkvb,
                    unsigned short* __restrict__ Wob,
                    unsigned short* __restrict__ W1b, unsigned short* __restrict__ W2b)
{
    int i = blockIdx.x * 256 + threadIdx.x;
    const float* src; unsigned short* dst; int off;
    if (i < (1 << 20))      { src = x;  dst = xb;  off = i; }
    else if (i < (2 << 20)) { src = W1; dst = W1b; off = i - (1 << 20); }
    else if (i < (3 << 20)) { src = W2; dst = W2b; off = i - (2 << 20); }
    else {
        int j = i - (3 << 20);
        int sel = j >> 18;
        off = j & ((1 << 18) - 1);
        src = sel == 0 ? Wq : sel == 1 ? Wk : sel == 2 ? Wv : Wo;
        dst = sel == 3 ? Wob : Wqkvb + ((size_t)sel << 20);
    }
    float4 v = ((const float4*)src)[off];
    ushort4 o = { f2b(v.x), f2b(v.y), f2b(v.z), f2b(v.w) };
    ((ushort4*)dst)[off] = o;
}

// ---------------- per-head relative-position bias by delta (T5 buckets, double math) ----------------
__global__ void rbias_kernel(const float* __restrict__ rel_emb, unsigned short* __restrict__ rbias)
{
    int idx = blockIdx.x * 256 + threadIdx.x;   // 16 * 2048
    if (idx >= 16 * 2048) return;
    int h = idx >> 11, q = idx & 2047;
    int n = q - 1023, ret = 0;                  // n = j - i
    if (n < 0) { ret = 16; n = -n; }
    int b;
    if (n < 8) b = n;
    else {
        double t = log((double)n / 8.0) / log(16.0) * 8.0;
        int v = 8 + (int)t;
        b = v < 15 ? v : 15;
    }
    rbias[idx] = f2b(rel_emb[(ret + b) * 16 + h]);
}

// ============ 128x128 MFMA GEMM, BK=64 + conflict-free swizzle + XCD swizzle ============
// Legacy round-7/8 loop structure (2 full-drain barriers per K-step) kept intact;
// changes vs legacy: (1) BK 32->64: half the barrier drains per unit K;
// (2) LDS layout [128][64] with chunk ^= (row&7) swizzle, applied on BOTH the
//     pre-swizzled global_load_lds source and the ds_read address (rule 21) —
//     measured 0 bank conflicts in round 3 (legacy pattern had 4.2M);
// (3) XCD-bijective block swizzle (all grids % 8 == 0) for L2 panel reuse.
// LDS 32KB static, ~4 blocks/CU — keeps the multi-block overlap that hides
// the remaining barrier drain (m114 wave-level overlap).
template<typename TC, typename TR, int RELU, int QKV>
__global__ __launch_bounds__(256)
void mfma_gemm(const unsigned short* __restrict__ A, int lda,
               const unsigned short* __restrict__ W, int ldw,
               const float* __restrict__ b0, const float* __restrict__ b1,
               const float* __restrict__ b2,
               const TR* __restrict__ res,
               void* __restrict__ C0, void* __restrict__ C1, void* __restrict__ C2,
               int ldc, int M, int N, int Ksplit)
{
    __shared__ unsigned short sm[2 * 128 * 64];   // 32KB: As + Ws, [128][64] each
    unsigned short* As = sm;
    unsigned short* Ws = sm + 128 * 64;

    const int tid = threadIdx.x;
    const int w = tid >> 6, lane = tid & 63;
    const int quad = lane >> 4, col = lane & 15;

    // XCD-bijective swizzle over the x-y grid (nwg % 8 == 0 for all launches here)
    const int bid = blockIdx.x + gridDim.x * blockIdx.y;
    const int nwg = gridDim.x * gridDim.y;
    const int swz = (bid & 7) * (nwg >> 3) + (bid >> 3);
    const int m0 = (swz / gridDim.x) * 128;
    const int n0 = (swz % gridDim.x) * 128;

    const int wrow = (w & 1) * 64, wcol = (w >> 1) * 64;
    const int kz = blockIdx.z * Ksplit;

    f32x4 acc[4][4] = {};

    for (int k0 = kz; k0 < kz + Ksplit; k0 += 64) {
        __syncthreads();
        // stage As/Ws [128][64]: 4 issues each per thread; linear LDS dest,
        // source chunk pre-swizzled with ^(row&7) so swizzled ds_reads match.
        #pragma unroll
        for (int l = 0; l < 4; ++l) {
            const int idx = l * 256 + tid;
            const int r = idx >> 3;
            const int c = (idx & 7) ^ (r & 7);
            unsigned off = (unsigned)__builtin_amdgcn_readfirstlane(
                (unsigned)((l * 256 + (tid & 192)) * 16));
            const unsigned short* ga = A + (size_t)(m0 + r) * lda + k0 + c * 8;
            __builtin_amdgcn_global_load_lds(
                (const __attribute__((address_space(1))) unsigned int*)ga,
                (__attribute__((address_space(3))) unsigned int*)((char*)As + off), 16, 0, 0);
            const unsigned short* gw = W + (size_t)(n0 + r) * ldw + k0 + c * 8;
            __builtin_amdgcn_global_load_lds(
                (const __attribute__((address_space(1))) unsigned int*)gw,
                (__attribute__((address_space(3))) unsigned int*)((char*)Ws + off), 16, 0, 0);
        }
        __syncthreads();   // full drain: staged data visible

        #pragma unroll
        for (int ks = 0; ks < 2; ++ks) {
            s8v af[4], bfr[4];
            #pragma unroll
            for (int mt = 0; mt < 4; ++mt) {
                int rr = wrow + mt * 16 + col;
                af[mt] = *(const s8v*)(As + rr * 64 + (((ks * 4 + quad) ^ (rr & 7)) << 3));
            }
            #pragma unroll
            for (int nt = 0; nt < 4; ++nt) {
                int rr = wcol + nt * 16 + col;
                bfr[nt] = *(const s8v*)(Ws + rr * 64 + (((ks * 4 + quad) ^ (rr & 7)) << 3));
            }
            #pragma unroll
            for (int mt = 0; mt < 4; ++mt)
                #pragma unroll
                for (int nt = 0; nt < 4; ++nt)
                    acc[mt][nt] = __builtin_amdgcn_mfma_f32_16x16x32_bf16(af[mt], bfr[nt], acc[mt][nt], 0, 0, 0);
        }
    }

    if (QKV) {
        const int sel = n0 >> 10;
        unsigned short* Cb = (unsigned short*)(sel == 0 ? C0 : sel == 1 ? C1 : C2);
        const float* bs = sel == 0 ? b0 : sel == 1 ? b1 : b2;
        #pragma unroll
        for (int mt = 0; mt < 4; ++mt)
            #pragma unroll
            for (int rg = 0; rg < 4; ++rg) {
                int gm = m0 + wrow + mt * 16 + quad * 4 + rg;
                #pragma unroll
                for (int nt = 0; nt < 4; ++nt) {
                    int gnc = (n0 + wcol + nt * 16 + col) & 1023;
                    Cb[(size_t)gm * 1024 + gnc] = f2b(acc[mt][nt][rg] + bs[gnc]);
                }
            }
    } else {
        void* Cv = blockIdx.z ? C1 : C0;
        const bool z0 = (blockIdx.z == 0);
        #pragma unroll
        for (int mt = 0; mt < 4; ++mt)
            #pragma unroll
            for (int rg = 0; rg < 4; ++rg) {
                int gm = m0 + wrow + mt * 16 + quad * 4 + rg;
                #pragma unroll
                for (int nt = 0; nt < 4; ++nt) {
                    int gn = n0 + wcol + nt * 16 + col;
                    float c = acc[mt][nt][rg];
                    if (z0) {
                        if (b0)  c += b0[gn];
                        if (res) c += to_f(res[(size_t)gm * ldc + gn]);
                    }
                    if (RELU) c = fmaxf(c, 0.f);
                    if (sizeof(TC) == 2) ((unsigned short*)Cv)[(size_t)gm * ldc + gn] = f2b(c);
                    else                 ((float*)Cv)[(size_t)gm * ldc + gn] = c;
                }
            }
    }
}

// ---------------- V transpose: vb bf16 [4096][1024] -> vt bf16 [bp][d][j] ----------------
__global__ __launch_bounds__(256)
void vtrans_kernel(const unsigned short* __restrict__ v, unsigned short* __restrict__ vt)
{
    __shared__ unsigned short t[64][68];
    const int bpmm = blockIdx.x;
    const int bp = bpmm >> 6, mm = bpmm & 63;
    const unsigned short* vr = v + (size_t)(bp * 64 + mm) * 1024;
    const int tid = threadIdx.x;
    #pragma unroll
    for (int it = 0; it < 4; ++it) {
        int c = (tid >> 6) + it * 4;
        int d = tid & 63;
        t[d][c] = vr[c * 64 + d];
    }
    __syncthreads();
    int d = tid >> 2, qq = tid & 3;
    ushort4 o = { t[d][qq * 4 + 0], t[d][qq * 4 + 1], t[d][qq * 4 + 2], t[d][qq * 4 + 3] };
    *(ushort4*)(vt + (size_t)bp * 65536 + (size_t)d * 1024 + mm * 16 + qq * 4) = o;
}

// ---------------- MFMA attention v3 (unchanged, proven) ----------------
__global__ __launch_bounds__(256, 2)
void attn_mfma_kernel(const unsigned short* __restrict__ qb,
                      const unsigned short* __restrict__ kb,
                      const unsigned short* __restrict__ vt,
                      const unsigned short* __restrict__ rbias,
                      const int* __restrict__ pmask,
                      unsigned short* __restrict__ att)
{
    __shared__ unsigned short Qs[128 * 64];
    __shared__ unsigned short KP[128 * 64];
    __shared__ unsigned short Vt[64 * 128];
    __shared__ unsigned short rbs[2048];
    __shared__ unsigned short pmls[1024];

    const int tid = threadIdx.x;
    const int w = tid >> 6, lane = tid & 63;
    const int quad = lane >> 4, col = lane & 15;
    const int bp = blockIdx.x, i0 = blockIdx.y * 128;
    const int h = bp & 15, bb = bp >> 4;
    const size_t base = (size_t)bp << 16;
    const int myrow0 = w * 32, myrow1 = w * 32 + 16;

    {
        const unsigned short* qg = qb + base + (size_t)i0 * 64;
        #pragma unroll
        for (int it = 0; it < 4; ++it) {
            int idx = it * 256 + tid;
            int r = idx >> 3, c = idx & 7;
            s8v d = *(const s8v*)(qg + (size_t)r * 64 + (c ^ (r & 7)) * 8);
            *(s8v*)(Qs + r * 64 + c * 8) = d;
        }
    }
    {
        const unsigned short* rg = rbias + h * 2048;
        #pragma unroll
        for (int it = 0; it < 8; ++it) rbs[it * 256 + tid] = rg[it * 256 + tid];
    }
    #pragma unroll
    for (int it = 0; it < 4; ++it) {
        int j = it * 256 + tid;
        pmls[j] = f2b(__logf((float)pmask[bb * 1024 + j]));
    }

    f32x4 O0[4] = {}, O1[4] = {};
    float lrow0[4] = {0.f, 0.f, 0.f, 0.f};
    float lrow1[4] = {0.f, 0.f, 0.f, 0.f};

    unsigned short* Pw = KP + w * 2048;

    for (int jt = 0; jt < 8; ++jt) {
        const int j0 = jt * 128;
        __syncthreads();
        {
            const unsigned short* kg = kb + base + (size_t)j0 * 64;
            #pragma unroll
            for (int it = 0; it < 4; ++it) {
                int idx = it * 256 + tid;
                int r = idx >> 3, c = idx & 7;
                s8v d = *(const s8v*)(kg + (size_t)r * 64 + (c ^ (r & 7)) * 8);
                *(s8v*)(KP + r * 64 + c * 8) = d;
            }
            const unsigned short* vg = vt + base + j0;
            #pragma unroll
            for (int it = 0; it < 4; ++it) {
                int idx = it * 256 + tid;
                int r = idx >> 4, c = idx & 15;
                s8v d = *(const s8v*)(vg + (size_t)r * 1024 + (c ^ (r & 15)) * 8);
                *(s8v*)(Vt + r * 128 + c * 8) = d;
            }
        }
        __syncthreads();

        f32x4 S0[8] = {}, S1[8] = {};
        #pragma unroll
        for (int ks = 0; ks < 2; ++ks) {
            int ar0 = myrow0 + col, ar1 = myrow1 + col;
            s8v a0 = *(const s8v*)(Qs + ar0 * 64 + (((ks * 4 + quad) ^ (ar0 & 7)) * 8));
            s8v a1 = *(const s8v*)(Qs + ar1 * 64 + (((ks * 4 + quad) ^ (ar1 & 7)) * 8));
            #pragma unroll
            for (int ct = 0; ct < 8; ++ct) {
                int br = ct * 16 + col;
                s8v b = *(const s8v*)(KP + br * 64 + (((ks * 4 + quad) ^ (br & 7)) * 8));
                S0[ct] = __builtin_amdgcn_mfma_f32_16x16x32_bf16(a0, b, S0[ct], 0, 0, 0);
                S1[ct] = __builtin_amdgcn_mfma_f32_16x16x32_bf16(a1, b, S1[ct], 0, 0, 0);
            }
        }

        #pragma unroll
        for (int ct = 0; ct < 8; ++ct) {
            int gj = j0 + ct * 16 + col;
            float pmv = bits2f(pmls[gj]);
            int d0 = gj - (i0 + myrow0 + quad * 4) + 1023;
            int d1 = gj - (i0 + myrow1 + quad * 4) + 1023;
            #pragma unroll
            for (int r = 0; r < 4; ++r) {
                float e0 = __expf(S0[ct][r] + bits2f(rbs[d0 - r]) + pmv);
                float e1 = __expf(S1[ct][r] + bits2f(rbs[d1 - r]) + pmv);
                S0[ct][r] = e0; lrow0[r] += e0;
                S1[ct][r] = e1; lrow1[r] += e1;
            }
        }

        __syncthreads();

        #pragma unroll
        for (int ct = 0; ct < 8; ++ct)
            #pragma unroll
            for (int r = 0; r < 4; ++r) {
                int lr = quad * 4 + r;
                int j = ct * 16 + col;
                Pw[lr * 128 + (((j >> 3) ^ lr) << 3) + (j & 7)] = f2b(S0[ct][r]);
            }
        #pragma unroll
        for (int kt = 0; kt < 4; ++kt) {
            int pr = col;
            s8v a = *(const s8v*)(Pw + pr * 128 + (((kt * 4 + quad) ^ pr) * 8));
            #pragma unroll
            for (int nt = 0; nt < 4; ++nt) {
                int vr = nt * 16 + col;
                s8v b = *(const s8v*)(Vt + vr * 128 + (((kt * 4 + quad) ^ (vr & 15)) * 8));
                O0[nt] = __builtin_amdgcn_mfma_f32_16x16x32_bf16(a, b, O0[nt], 0, 0, 0);
            }
        }

        #pragma unroll
        for (int ct = 0; ct < 8; ++ct)
            #pragma unroll
            for (int r = 0; r < 4; ++r) {
                int lr = quad * 4 + r;
                int j = ct * 16 + col;
                Pw[lr * 128 + (((j >> 3) ^ lr) << 3) + (j & 7)] = f2b(S1[ct][r]);
            }
        #pragma unroll
        for (int kt = 0; kt < 4; ++kt) {
            int pr = col;
            s8v a = *(const s8v*)(Pw + pr * 128 + (((kt * 4 + quad) ^ pr) * 8));
            #pragma unroll
            for (int nt = 0; nt < 4; ++nt) {
                int vr = nt * 16 + col;
                s8v b = *(const s8v*)(Vt + vr * 128 + (((kt * 4 + quad) ^ (vr & 15)) * 8));
                O1[nt] = __builtin_amdgcn_mfma_f32_16x16x32_bf16(a, b, O1[nt], 0, 0, 0);
            }
        }
    }

    #pragma unroll
    for (int off = 1; off < 16; off <<= 1)
        #pragma unroll
        for (int r = 0; r < 4; ++r) {
            lrow0[r] += __shfl_xor(lrow0[r], off);
            lrow1[r] += __shfl_xor(lrow1[r], off);
        }
    #pragma unroll
    for (int r = 0; r < 4; ++r) {
        lrow0[r] = 1.f / lrow0[r];
        lrow1[r] = 1.f / lrow1[r];
    }

    unsigned short* ag0 = att + base + (size_t)(i0 + myrow0) * 64;
    unsigned short* ag1 = att + base + (size_t)(i0 + myrow1) * 64;
    #pragma unroll
    for (int nt = 0; nt < 4; ++nt)
        #pragma unroll
        for (int r = 0; r < 4; ++r) {
            ag0[(size_t)(quad * 4 + r) * 64 + nt * 16 + col] = f2b(O0[nt][r] * lrow0[r]);
            ag1[(size_t)(quad * 4 + r) * 64 + nt * 16 + col] = f2b(O1[nt][r] * lrow1[r]);
        }
}

// ---------------- layernorm over rows of 1024: in1+in2 -> (outF fp32, outB bf16) ----------------
template<typename TIN>
__global__ __launch_bounds__(256)
void ln_kernel(const TIN* __restrict__ in1, const TIN* __restrict__ in2,
               float* __restrict__ outF, unsigned short* __restrict__ outB)
{
    __shared__ float sred[8];
    const int row = blockIdx.x;
    const int tid = threadIdx.x;
    const size_t off = (size_t)row * 1024 + tid * 4;
    float a[4];
    load4(in1 + off, a);
    if (in2) {
        float b[4];
        load4(in2 + off, b);
        #pragma unroll
        for (int i = 0; i < 4; ++i) a[i] += b[i];
    }

    float lsum = a[0] + a[1] + a[2] + a[3];
    #pragma unroll
    for (int o = 32; o; o >>= 1) lsum += __shfl_down(lsum, o);
    const int lane = tid & 63, wid = tid >> 6;
    if (lane == 0) sred[wid] = lsum;
    __syncthreads();
    if (tid == 0) sred[4] = (sred[0] + sred[1] + sred[2] + sred[3]) * (1.f / 1024.f);
    __syncthreads();
    const float mean = sred[4];

    float d0 = a[0] - mean, d1 = a[1] - mean, d2 = a[2] - mean, d3 = a[3] - mean;
    float lsq = d0 * d0 + d1 * d1 + d2 * d2 + d3 * d3;
    #pragma unroll
    for (int o = 32; o; o >>= 1) lsq += __shfl_down(lsq, o);
    __syncthreads();
    if (lane == 0) sred[wid] = lsq;
    __syncthreads();
    if (tid == 0) sred[5] = rsqrtf((sred[0] + sred[1] + sred[2] + sred[3]) * (1.f / 1024.f));
    __syncthreads();
    const float r = sred[5];

    float o0 = d0 * r, o1 = d1 * r, o2 = d2 * r, o3 = d3 * r;
    if (outF) {
        float4 o = {o0, o1, o2, o3};
        *(float4*)&outF[off] = o;
    }
    if (outB) {
        ushort4 o = { f2b(o0), f2b(o1), f2b(o2), f2b(o3) };
        *(ushort4*)&outB[off] = o;
    }
}

extern "C" void kernel_launch(void* const* d_in, const int* in_sizes, int n_in,
                              void* d_out, int out_size, void* d_ws, size_t ws_size,
                              hipStream_t stream)
{
    const float* x     = (const float*)d_in[0];
    const int*   pmask = (const int*)  d_in[1];
    const float* Wq    = (const float*)d_in[2];
    const float* bq    = (const float*)d_in[3];
    const float* Wk    = (const float*)d_in[4];
    const float* bk    = (const float*)d_in[5];
    const float* Wv    = (const float*)d_in[6];
    const float* bv    = (const float*)d_in[7];
    const float* Wo    = (const float*)d_in[8];
    const float* bo    = (const float*)d_in[9];
    const float* rel   = (const float*)d_in[10];
    const float* W1    = (const float*)d_in[11];
    const float* b1    = (const float*)d_in[12];
    const float* W2    = (const float*)d_in[13];
    const float* b2    = (const float*)d_in[14];

    const int M = 4096, D = 1024;
    dim3 blk(256);

    // ---- workspace map (identical to round-7/8-proven; peak write 64MB+64KB) ----
    char* ws = (char*)d_ws;
    unsigned short* W1b   = (unsigned short*)(ws);                 // 0-8
    unsigned short* W2b   = (unsigned short*)(ws + ( 8u << 20));   // 8-16
    unsigned short* xb    = (unsigned short*)(ws + (16u << 20));   // 16-24
    unsigned short* Wqkvb = (unsigned short*)(ws + (24u << 20));   // 24-30
    unsigned short* Wob   = (unsigned short*)(ws + (30u << 20));   // 30-32
    unsigned short* qb    = (unsigned short*)(ws + (32u << 20));   // 32-40
    unsigned short* kb    = (unsigned short*)(ws + (40u << 20));   // 40-48
    unsigned short* vb    = (unsigned short*)(ws + (48u << 20));   // 48-56
    unsigned short* vt    = (unsigned short*)(ws + (56u << 20));   // 56-64
    unsigned short* rbias = (unsigned short*)(ws + (64u << 20));   // 64-64.0625
    float*          tmpA    = (float*)(ws + (32u << 20));          // 32-48 (qb/kb dead after attn)
    float*          tmpB    = (float*)(ws + (48u << 20));          // 48-64 (vb/vt dead after attn)
    unsigned short* attoutB = (unsigned short*)(ws + (16u << 20)); // 16-24 (xb dead after qkv)
    unsigned short* ff1     = (unsigned short*)(ws + (32u << 20)); // 32-64 (tmpA/B dead after ln1)
    unsigned short* ff2a    = (unsigned short*)(ws);               // 0-8   (W1b dead after ff1)
    unsigned short* ff2b    = (unsigned short*)(ws + (24u << 20)); // 24-32 (Wqkvb/Wob dead)
    unsigned short* attb    = (unsigned short*)d_out;              // d_out scratch (proven)

    // ---- conversions / tables ----
    cvt_all_kernel<<<16384, blk, 0, stream>>>(x, Wq, Wk, Wv, Wo, W1, W2,
                                              xb, Wqkvb, Wob, W1b, W2b);
    rbias_kernel<<<128, blk, 0, stream>>>(rel, rbias);

    // ---- fused QKV projection: N=3072, routed to qb/kb/vb ----
    mfma_gemm<unsigned short, float, 0, 1><<<dim3(24, 32), blk, 0, stream>>>(
        xb, D, Wqkvb, D, bq, bk, bv, (const float*)nullptr, qb, kb, vb, D, M, 3072, D);

    vtrans_kernel<<<4096, blk, 0, stream>>>(vb, vt);

    // ---- attention v3: 128-query tiles, bp-major grid, 2 blocks/CU even ----
    attn_mfma_kernel<<<dim3(64, 8), blk, 0, stream>>>(qb, kb, vt, rbias, pmask, attb);

    // ---- Wo projection + residual x, split-K z=2 -> tmpA/tmpB fp32; LN1 -> attoutB ----
    mfma_gemm<float, float, 0, 0><<<dim3(8, 32, 2), blk, 0, stream>>>(
        attb, D, Wob, D, bo, nullptr, nullptr, x, tmpA, tmpB, nullptr, D, M, D, 512);
    ln_kernel<float><<<4096, blk, 0, stream>>>(tmpA, tmpB, nullptr, attoutB);

    // ---- FFN: ff1 full N=4096; ff2 split-K z=2 (res = attoutB bf16); LN2 sums ----
    mfma_gemm<unsigned short, float, 1, 0><<<dim3(32, 32), blk, 0, stream>>>(
        attoutB, D, W1b, D, b1, nullptr, nullptr, (const float*)nullptr,
        ff1, nullptr, nullptr, 4096, M, 4096, D);
    mfma_gemm<unsigned short, unsigned short, 0, 0><<<dim3(8, 32, 2), blk, 0, stream>>>(
        ff1, 4096, W2b, 4096, b2, nullptr, nullptr, attoutB, ff2a, ff2b, nullptr, D, M, D, 2048);
    ln_kernel<unsigned short><<<4096, blk, 0, stream>>>(ff2a, ff2b, (float*)d_out, nullptr);
}

// Round 5
// 403.189 us; speedup vs baseline: 1.1485x; 1.0302x over previous
//
#include <hip/hip_runtime.h>
#include <hip/hip_bf16.h>

typedef __hip_bfloat16 bf16;
typedef __attribute__((ext_vector_type(8))) short s8v;      // 8 bf16 (4 VGPRs) MFMA A/B frag
typedef __attribute__((ext_vector_type(4))) float f32x4;    // MFMA C/D frag

__device__ __forceinline__ float bits2f(unsigned short u) {
    return __uint_as_float(((unsigned)u) << 16);
}
__device__ __forceinline__ unsigned short f2b(float f) {   // fp32 -> bf16 RNE
    union { float f; unsigned u; } x{f};
    return (unsigned short)((x.u + 0x7fff + ((x.u >> 16) & 1)) >> 16);
}
__device__ __forceinline__ float to_f(float x) { return x; }
__device__ __forceinline__ float to_f(unsigned short x) { return bits2f(x); }

__device__ __forceinline__ void load4(const float* p, float* a) {
    float4 t = *(const float4*)p;
    a[0] = t.x; a[1] = t.y; a[2] = t.z; a[3] = t.w;
}
__device__ __forceinline__ void load4(const unsigned short* p, float* a) {
    ushort4 t = *(const ushort4*)p;
    a[0] = bits2f(t.x); a[1] = bits2f(t.y); a[2] = bits2f(t.z); a[3] = bits2f(t.w);
}

// ---------------- fused fp32 -> bf16 convert of x + all weights ----------------
__global__ __launch_bounds__(256)
void cvt_all_kernel(const float* __restrict__ x,
                    const float* __restrict__ Wq, const float* __restrict__ Wk,
                    const float* __restrict__ Wv, const float* __restrict__ Wo,
                    const float* __restrict__ W1, const float* __restrict__ W2,
                    unsigned short* __restrict__ xb, unsigned short* __restrict__ Wqkvb,
                    unsigned short* __restrict__ Wob,
                    unsigned short* __restrict__ W1b, unsigned short* __restrict__ W2b)
{
    int i = blockIdx.x * 256 + threadIdx.x;
    const float* src; unsigned short* dst; int off;
    if (i < (1 << 20))      { src = x;  dst = xb;  off = i; }
    else if (i < (2 << 20)) { src = W1; dst = W1b; off = i - (1 << 20); }
    else if (i < (3 << 20)) { src = W2; dst = W2b; off = i - (2 << 20); }
    else {
        int j = i - (3 << 20);
        int sel = j >> 18;
        off = j & ((1 << 18) - 1);
        src = sel == 0 ? Wq : sel == 1 ? Wk : sel == 2 ? Wv : Wo;
        dst = sel == 3 ? Wob : Wqkvb + ((size_t)sel << 20);
    }
    float4 v = ((const float4*)src)[off];
    ushort4 o = { f2b(v.x), f2b(v.y), f2b(v.z), f2b(v.w) };
    ((ushort4*)dst)[off] = o;
}

// ---------------- per-head relative-position bias by delta (T5 buckets, double math) ----------------
__global__ void rbias_kernel(const float* __restrict__ rel_emb, unsigned short* __restrict__ rbias)
{
    int idx = blockIdx.x * 256 + threadIdx.x;   // 16 * 2048
    if (idx >= 16 * 2048) return;
    int h = idx >> 11, q = idx & 2047;
    int n = q - 1023, ret = 0;                  // n = j - i
    if (n < 0) { ret = 16; n = -n; }
    int b;
    if (n < 8) b = n;
    else {
        double t = log((double)n / 8.0) / log(16.0) * 8.0;
        int v = 8 + (int)t;
        b = v < 15 ? v : 15;
    }
    rbias[idx] = f2b(rel_emb[(ret + b) * 16 + h]);
}

// ============ 128x128 MFMA GEMM, BK=32 double-buffered (T3-minimum 2-phase) ============
// vs round-4 (BK=64, single-buffer, 2 drains/step, 70.4us): same 32KB LDS and
// ~5 blocks/CU, same conflict-free both-sides swizzle (measured 0 conflicts),
// same XCD-bijective block swizzle; ONE change: next-tile staging is issued
// BEFORE the compute phase into the other buffer, so the vmcnt(0) drain at the
// next __syncthreads waits on loads that have had a full MFMA phase to land
// (T3-minimum recipe). Barriers per unit K unchanged (1 per 32-K).
template<typename TC, typename TR, int RELU, int QKV>
__global__ __launch_bounds__(256)
void mfma_gemm(const unsigned short* __restrict__ A, int lda,
               const unsigned short* __restrict__ W, int ldw,
               const float* __restrict__ b0, const float* __restrict__ b1,
               const float* __restrict__ b2,
               const TR* __restrict__ res,
               void* __restrict__ C0, void* __restrict__ C1, void* __restrict__ C2,
               int ldc, int M, int N, int Ksplit)
{
    __shared__ unsigned short sm[4 * 128 * 32];   // 32KB: As[2] + Ws[2], [128][32] each
    const int tid = threadIdx.x;
    const int w = tid >> 6, lane = tid & 63;
    const int quad = lane >> 4, col = lane & 15;

    // XCD-bijective swizzle over the x-y grid (nwg % 8 == 0 for all launches here)
    const int bid = blockIdx.x + gridDim.x * blockIdx.y;
    const int nwg = gridDim.x * gridDim.y;
    const int swz = (bid & 7) * (nwg >> 3) + (bid >> 3);
    const int m0 = (swz / gridDim.x) * 128;
    const int n0 = (swz % gridDim.x) * 128;

    const int wrow = (w & 1) * 64, wcol = (w >> 1) * 64;
    const int kz = blockIdx.z * Ksplit;
    const int NT = Ksplit >> 5;

    // staging geometry: [128][32] per matrix = 512 x 16B; 2 issues/thread/matrix.
    // linear LDS dest (wave-uniform base + lane*16); global chunk pre-swizzled
    // with ^(row&3) so the swizzled ds_reads below see the right data (rule 21).
    const int sr0 = (0 * 256 + tid) >> 2,  sc0 = ((0 * 256 + tid) & 3) ^ (sr0 & 3);
    const int sr1 = (1 * 256 + tid) >> 2,  sc1 = ((1 * 256 + tid) & 3) ^ (sr1 & 3);
    const unsigned off0 = (unsigned)__builtin_amdgcn_readfirstlane((unsigned)((0 * 256 + (tid & 192)) * 16));
    const unsigned off1 = (unsigned)__builtin_amdgcn_readfirstlane((unsigned)((1 * 256 + (tid & 192)) * 16));

#define STAGE32(buf, k0)                                                                     \
    {                                                                                        \
        unsigned short* As_ = sm + (buf) * 4096;                                             \
        unsigned short* Ws_ = sm + 8192 + (buf) * 4096;                                      \
        const unsigned short* ga0 = A + (size_t)(m0 + sr0) * lda + (k0) + sc0 * 8;           \
        __builtin_amdgcn_global_load_lds(                                                    \
            (const __attribute__((address_space(1))) unsigned int*)ga0,                      \
            (__attribute__((address_space(3))) unsigned int*)((char*)As_ + off0), 16, 0, 0); \
        const unsigned short* ga1 = A + (size_t)(m0 + sr1) * lda + (k0) + sc1 * 8;           \
        __builtin_amdgcn_global_load_lds(                                                    \
            (const __attribute__((address_space(1))) unsigned int*)ga1,                      \
            (__attribute__((address_space(3))) unsigned int*)((char*)As_ + off1), 16, 0, 0); \
        const unsigned short* gw0 = W + (size_t)(n0 + sr0) * ldw + (k0) + sc0 * 8;           \
        __builtin_amdgcn_global_load_lds(                                                    \
            (const __attribute__((address_space(1))) unsigned int*)gw0,                      \
            (__attribute__((address_space(3))) unsigned int*)((char*)Ws_ + off0), 16, 0, 0); \
        const unsigned short* gw1 = W + (size_t)(n0 + sr1) * ldw + (k0) + sc1 * 8;           \
        __builtin_amdgcn_global_load_lds(                                                    \
            (const __attribute__((address_space(1))) unsigned int*)gw1,                      \
            (__attribute__((address_space(3))) unsigned int*)((char*)Ws_ + off1), 16, 0, 0); \
    }

    f32x4 acc[4][4] = {};

    STAGE32(0, kz);                      // prologue: tile 0 -> buf 0

    for (int t = 0; t < NT; ++t) {
        __syncthreads();                 // drains buf[cur] staging (issued one phase ago)
        const int cur = t & 1;
        if (t + 1 < NT) STAGE32(cur ^ 1, kz + (t + 1) * 32);   // issue-early (T3)

        const unsigned short* As = sm + cur * 4096;
        const unsigned short* Ws = sm + 8192 + cur * 4096;
        s8v af[4], bfr[4];
        #pragma unroll
        for (int mt = 0; mt < 4; ++mt) {
            int rr = wrow + mt * 16 + col;
            af[mt] = *(const s8v*)(As + rr * 32 + ((quad ^ (rr & 3)) << 3));
        }
        #pragma unroll
        for (int nt = 0; nt < 4; ++nt) {
            int rr = wcol + nt * 16 + col;
            bfr[nt] = *(const s8v*)(Ws + rr * 32 + ((quad ^ (rr & 3)) << 3));
        }
        __builtin_amdgcn_s_setprio(1);
        #pragma unroll
        for (int mt = 0; mt < 4; ++mt)
            #pragma unroll
            for (int nt = 0; nt < 4; ++nt)
                acc[mt][nt] = __builtin_amdgcn_mfma_f32_16x16x32_bf16(af[mt], bfr[nt], acc[mt][nt], 0, 0, 0);
        __builtin_amdgcn_s_setprio(0);
    }
#undef STAGE32

    if (QKV) {
        const int sel = n0 >> 10;
        unsigned short* Cb = (unsigned short*)(sel == 0 ? C0 : sel == 1 ? C1 : C2);
        const float* bs = sel == 0 ? b0 : sel == 1 ? b1 : b2;
        #pragma unroll
        for (int mt = 0; mt < 4; ++mt)
            #pragma unroll
            for (int rg = 0; rg < 4; ++rg) {
                int gm = m0 + wrow + mt * 16 + quad * 4 + rg;
                #pragma unroll
                for (int nt = 0; nt < 4; ++nt) {
                    int gnc = (n0 + wcol + nt * 16 + col) & 1023;
                    Cb[(size_t)gm * 1024 + gnc] = f2b(acc[mt][nt][rg] + bs[gnc]);
                }
            }
    } else {
        void* Cv = blockIdx.z ? C1 : C0;
        const bool z0 = (blockIdx.z == 0);
        #pragma unroll
        for (int mt = 0; mt < 4; ++mt)
            #pragma unroll
            for (int rg = 0; rg < 4; ++rg) {
                int gm = m0 + wrow + mt * 16 + quad * 4 + rg;
                #pragma unroll
                for (int nt = 0; nt < 4; ++nt) {
                    int gn = n0 + wcol + nt * 16 + col;
                    float c = acc[mt][nt][rg];
                    if (z0) {
                        if (b0)  c += b0[gn];
                        if (res) c += to_f(res[(size_t)gm * ldc + gn]);
                    }
                    if (RELU) c = fmaxf(c, 0.f);
                    if (sizeof(TC) == 2) ((unsigned short*)Cv)[(size_t)gm * ldc + gn] = f2b(c);
                    else                 ((float*)Cv)[(size_t)gm * ldc + gn] = c;
                }
            }
    }
}

// ---------------- V transpose: vb bf16 [4096][1024] -> vt bf16 [bp][d][j] ----------------
__global__ __launch_bounds__(256)
void vtrans_kernel(const unsigned short* __restrict__ v, unsigned short* __restrict__ vt)
{
    __shared__ unsigned short t[64][68];
    const int bpmm = blockIdx.x;
    const int bp = bpmm >> 6, mm = bpmm & 63;
    const unsigned short* vr = v + (size_t)(bp * 64 + mm) * 1024;
    const int tid = threadIdx.x;
    #pragma unroll
    for (int it = 0; it < 4; ++it) {
        int c = (tid >> 6) + it * 4;
        int d = tid & 63;
        t[d][c] = vr[c * 64 + d];
    }
    __syncthreads();
    int d = tid >> 2, qq = tid & 3;
    ushort4 o = { t[d][qq * 4 + 0], t[d][qq * 4 + 1], t[d][qq * 4 + 2], t[d][qq * 4 + 3] };
    *(ushort4*)(vt + (size_t)bp * 65536 + (size_t)d * 1024 + mm * 16 + qq * 4) = o;
}

// ---------------- MFMA attention v3 (unchanged, proven) ----------------
__global__ __launch_bounds__(256, 2)
void attn_mfma_kernel(const unsigned short* __restrict__ qb,
                      const unsigned short* __restrict__ kb,
                      const unsigned short* __restrict__ vt,
                      const unsigned short* __restrict__ rbias,
                      const int* __restrict__ pmask,
                      unsigned short* __restrict__ att)
{
    __shared__ unsigned short Qs[128 * 64];
    __shared__ unsigned short KP[128 * 64];
    __shared__ unsigned short Vt[64 * 128];
    __shared__ unsigned short rbs[2048];
    __shared__ unsigned short pmls[1024];

    const int tid = threadIdx.x;
    const int w = tid >> 6, lane = tid & 63;
    const int quad = lane >> 4, col = lane & 15;
    const int bp = blockIdx.x, i0 = blockIdx.y * 128;
    const int h = bp & 15, bb = bp >> 4;
    const size_t base = (size_t)bp << 16;
    const int myrow0 = w * 32, myrow1 = w * 32 + 16;

    {
        const unsigned short* qg = qb + base + (size_t)i0 * 64;
        #pragma unroll
        for (int it = 0; it < 4; ++it) {
            int idx = it * 256 + tid;
            int r = idx >> 3, c = idx & 7;
            s8v d = *(const s8v*)(qg + (size_t)r * 64 + (c ^ (r & 7)) * 8);
            *(s8v*)(Qs + r * 64 + c * 8) = d;
        }
    }
    {
        const unsigned short* rg = rbias + h * 2048;
        #pragma unroll
        for (int it = 0; it < 8; ++it) rbs[it * 256 + tid] = rg[it * 256 + tid];
    }
    #pragma unroll
    for (int it = 0; it < 4; ++it) {
        int j = it * 256 + tid;
        pmls[j] = f2b(__logf((float)pmask[bb * 1024 + j]));
    }

    f32x4 O0[4] = {}, O1[4] = {};
    float lrow0[4] = {0.f, 0.f, 0.f, 0.f};
    float lrow1[4] = {0.f, 0.f, 0.f, 0.f};

    unsigned short* Pw = KP + w * 2048;

    for (int jt = 0; jt < 8; ++jt) {
        const int j0 = jt * 128;
        __syncthreads();
        {
            const unsigned short* kg = kb + base + (size_t)j0 * 64;
            #pragma unroll
            for (int it = 0; it < 4; ++it) {
                int idx = it * 256 + tid;
                int r = idx >> 3, c = idx & 7;
                s8v d = *(const s8v*)(kg + (size_t)r * 64 + (c ^ (r & 7)) * 8);
                *(s8v*)(KP + r * 64 + c * 8) = d;
            }
            const unsigned short* vg = vt + base + j0;
            #pragma unroll
            for (int it = 0; it < 4; ++it) {
                int idx = it * 256 + tid;
                int r = idx >> 4, c = idx & 15;
                s8v d = *(const s8v*)(vg + (size_t)r * 1024 + (c ^ (r & 15)) * 8);
                *(s8v*)(Vt + r * 128 + c * 8) = d;
            }
        }
        __syncthreads();

        f32x4 S0[8] = {}, S1[8] = {};
        #pragma unroll
        for (int ks = 0; ks < 2; ++ks) {
            int ar0 = myrow0 + col, ar1 = myrow1 + col;
            s8v a0 = *(const s8v*)(Qs + ar0 * 64 + (((ks * 4 + quad) ^ (ar0 & 7)) * 8));
            s8v a1 = *(const s8v*)(Qs + ar1 * 64 + (((ks * 4 + quad) ^ (ar1 & 7)) * 8));
            #pragma unroll
            for (int ct = 0; ct < 8; ++ct) {
                int br = ct * 16 + col;
                s8v b = *(const s8v*)(KP + br * 64 + (((ks * 4 + quad) ^ (br & 7)) * 8));
                S0[ct] = __builtin_amdgcn_mfma_f32_16x16x32_bf16(a0, b, S0[ct], 0, 0, 0);
                S1[ct] = __builtin_amdgcn_mfma_f32_16x16x32_bf16(a1, b, S1[ct], 0, 0, 0);
            }
        }

        #pragma unroll
        for (int ct = 0; ct < 8; ++ct) {
            int gj = j0 + ct * 16 + col;
            float pmv = bits2f(pmls[gj]);
            int d0 = gj - (i0 + myrow0 + quad * 4) + 1023;
            int d1 = gj - (i0 + myrow1 + quad * 4) + 1023;
            #pragma unroll
            for (int r = 0; r < 4; ++r) {
                float e0 = __expf(S0[ct][r] + bits2f(rbs[d0 - r]) + pmv);
                float e1 = __expf(S1[ct][r] + bits2f(rbs[d1 - r]) + pmv);
                S0[ct][r] = e0; lrow0[r] += e0;
                S1[ct][r] = e1; lrow1[r] += e1;
            }
        }

        __syncthreads();

        #pragma unroll
        for (int ct = 0; ct < 8; ++ct)
            #pragma unroll
            for (int r = 0; r < 4; ++r) {
                int lr = quad * 4 + r;
                int j = ct * 16 + col;
                Pw[lr * 128 + (((j >> 3) ^ lr) << 3) + (j & 7)] = f2b(S0[ct][r]);
            }
        #pragma unroll
        for (int kt = 0; kt < 4; ++kt) {
            int pr = col;
            s8v a = *(const s8v*)(Pw + pr * 128 + (((kt * 4 + quad) ^ pr) * 8));
            #pragma unroll
            for (int nt = 0; nt < 4; ++nt) {
                int vr = nt * 16 + col;
                s8v b = *(const s8v*)(Vt + vr * 128 + (((kt * 4 + quad) ^ (vr & 15)) * 8));
                O0[nt] = __builtin_amdgcn_mfma_f32_16x16x32_bf16(a, b, O0[nt], 0, 0, 0);
            }
        }

        #pragma unroll
        for (int ct = 0; ct < 8; ++ct)
            #pragma unroll
            for (int r = 0; r < 4; ++r) {
                int lr = quad * 4 + r;
                int j = ct * 16 + col;
                Pw[lr * 128 + (((j >> 3) ^ lr) << 3) + (j & 7)] = f2b(S1[ct][r]);
            }
        #pragma unroll
        for (int kt = 0; kt < 4; ++kt) {
            int pr = col;
            s8v a = *(const s8v*)(Pw + pr * 128 + (((kt * 4 + quad) ^ pr) * 8));
            #pragma unroll
            for (int nt = 0; nt < 4; ++nt) {
                int vr = nt * 16 + col;
                s8v b = *(const s8v*)(Vt + vr * 128 + (((kt * 4 + quad) ^ (vr & 15)) * 8));
                O1[nt] = __builtin_amdgcn_mfma_f32_16x16x32_bf16(a, b, O1[nt], 0, 0, 0);
            }
        }
    }

    #pragma unroll
    for (int off = 1; off < 16; off <<= 1)
        #pragma unroll
        for (int r = 0; r < 4; ++r) {
            lrow0[r] += __shfl_xor(lrow0[r], off);
            lrow1[r] += __shfl_xor(lrow1[r], off);
        }
    #pragma unroll
    for (int r = 0; r < 4; ++r) {
        lrow0[r] = 1.f / lrow0[r];
        lrow1[r] = 1.f / lrow1[r];
    }

    unsigned short* ag0 = att + base + (size_t)(i0 + myrow0) * 64;
    unsigned short* ag1 = att + base + (size_t)(i0 + myrow1) * 64;
    #pragma unroll
    for (int nt = 0; nt < 4; ++nt)
        #pragma unroll
        for (int r = 0; r < 4; ++r) {
            ag0[(size_t)(quad * 4 + r) * 64 + nt * 16 + col] = f2b(O0[nt][r] * lrow0[r]);
            ag1[(size_t)(quad * 4 + r) * 64 + nt * 16 + col] = f2b(O1[nt][r] * lrow1[r]);
        }
}

// ---------------- layernorm over rows of 1024: in1+in2 -> (outF fp32, outB bf16) ----------------
template<typename TIN>
__global__ __launch_bounds__(256)
void ln_kernel(const TIN* __restrict__ in1, const TIN* __restrict__ in2,
               float* __restrict__ outF, unsigned short* __restrict__ outB)
{
    __shared__ float sred[8];
    const int row = blockIdx.x;
    const int tid = threadIdx.x;
    const size_t off = (size_t)row * 1024 + tid * 4;
    float a[4];
    load4(in1 + off, a);
    if (in2) {
        float b[4];
        load4(in2 + off, b);
        #pragma unroll
        for (int i = 0; i < 4; ++i) a[i] += b[i];
    }

    float lsum = a[0] + a[1] + a[2] + a[3];
    #pragma unroll
    for (int o = 32; o; o >>= 1) lsum += __shfl_down(lsum, o);
    const int lane = tid & 63, wid = tid >> 6;
    if (lane == 0) sred[wid] = lsum;
    __syncthreads();
    if (tid == 0) sred[4] = (sred[0] + sred[1] + sred[2] + sred[3]) * (1.f / 1024.f);
    __syncthreads();
    const float mean = sred[4];

    float d0 = a[0] - mean, d1 = a[1] - mean, d2 = a[2] - mean, d3 = a[3] - mean;
    float lsq = d0 * d0 + d1 * d1 + d2 * d2 + d3 * d3;
    #pragma unroll
    for (int o = 32; o; o >>= 1) lsq += __shfl_down(lsq, o);
    __syncthreads();
    if (lane == 0) sred[wid] = lsq;
    __syncthreads();
    if (tid == 0) sred[5] = rsqrtf((sred[0] + sred[1] + sred[2] + sred[3]) * (1.f / 1024.f));
    __syncthreads();
    const float r = sred[5];

    float o0 = d0 * r, o1 = d1 * r, o2 = d2 * r, o3 = d3 * r;
    if (outF) {
        float4 o = {o0, o1, o2, o3};
        *(float4*)&outF[off] = o;
    }
    if (outB) {
        ushort4 o = { f2b(o0), f2b(o1), f2b(o2), f2b(o3) };
        *(ushort4*)&outB[off] = o;
    }
}

extern "C" void kernel_launch(void* const* d_in, const int* in_sizes, int n_in,
                              void* d_out, int out_size, void* d_ws, size_t ws_size,
                              hipStream_t stream)
{
    const float* x     = (const float*)d_in[0];
    const int*   pmask = (const int*)  d_in[1];
    const float* Wq    = (const float*)d_in[2];
    const float* bq    = (const float*)d_in[3];
    const float* Wk    = (const float*)d_in[4];
    const float* bk    = (const float*)d_in[5];
    const float* Wv    = (const float*)d_in[6];
    const float* bv    = (const float*)d_in[7];
    const float* Wo    = (const float*)d_in[8];
    const float* bo    = (const float*)d_in[9];
    const float* rel   = (const float*)d_in[10];
    const float* W1    = (const float*)d_in[11];
    const float* b1    = (const float*)d_in[12];
    const float* W2    = (const float*)d_in[13];
    const float* b2    = (const float*)d_in[14];

    const int M = 4096, D = 1024;
    dim3 blk(256);

    // ---- workspace map (identical to round-7/8-proven; peak write 64MB+64KB) ----
    char* ws = (char*)d_ws;
    unsigned short* W1b   = (unsigned short*)(ws);                 // 0-8
    unsigned short* W2b   = (unsigned short*)(ws + ( 8u << 20));   // 8-16
    unsigned short* xb    = (unsigned short*)(ws + (16u << 20));   // 16-24
    unsigned short* Wqkvb = (unsigned short*)(ws + (24u << 20));   // 24-30
    unsigned short* Wob   = (unsigned short*)(ws + (30u << 20));   // 30-32
    unsigned short* qb    = (unsigned short*)(ws + (32u << 20));   // 32-40
    unsigned short* kb    = (unsigned short*)(ws + (40u << 20));   // 40-48
    unsigned short* vb    = (unsigned short*)(ws + (48u << 20));   // 48-56
    unsigned short* vt    = (unsigned short*)(ws + (56u << 20));   // 56-64
    unsigned short* rbias = (unsigned short*)(ws + (64u << 20));   // 64-64.0625
    float*          tmpA    = (float*)(ws + (32u << 20));          // 32-48 (qb/kb dead after attn)
    float*          tmpB    = (float*)(ws + (48u << 20));          // 48-64 (vb/vt dead after attn)
    unsigned short* attoutB = (unsigned short*)(ws + (16u << 20)); // 16-24 (xb dead after qkv)
    unsigned short* ff1     = (unsigned short*)(ws + (32u << 20)); // 32-64 (tmpA/B dead after ln1)
    unsigned short* ff2a    = (unsigned short*)(ws);               // 0-8   (W1b dead after ff1)
    unsigned short* ff2b    = (unsigned short*)(ws + (24u << 20)); // 24-32 (Wqkvb/Wob dead)
    unsigned short* attb    = (unsigned short*)d_out;              // d_out scratch (proven)

    // ---- conversions / tables ----
    cvt_all_kernel<<<16384, blk, 0, stream>>>(x, Wq, Wk, Wv, Wo, W1, W2,
                                              xb, Wqkvb, Wob, W1b, W2b);
    rbias_kernel<<<128, blk, 0, stream>>>(rel, rbias);

    // ---- fused QKV projection: N=3072, routed to qb/kb/vb ----
    mfma_gemm<unsigned short, float, 0, 1><<<dim3(24, 32), blk, 0, stream>>>(
        xb, D, Wqkvb, D, bq, bk, bv, (const float*)nullptr, qb, kb, vb, D, M, 3072, D);

    vtrans_kernel<<<4096, blk, 0, stream>>>(vb, vt);

    // ---- attention v3: 128-query tiles, bp-major grid, 2 blocks/CU even ----
    attn_mfma_kernel<<<dim3(64, 8), blk, 0, stream>>>(qb, kb, vt, rbias, pmask, attb);

    // ---- Wo projection + residual x, split-K z=2 -> tmpA/tmpB fp32; LN1 -> attoutB ----
    mfma_gemm<float, float, 0, 0><<<dim3(8, 32, 2), blk, 0, stream>>>(
        attb, D, Wob, D, bo, nullptr, nullptr, x, tmpA, tmpB, nullptr, D, M, D, 512);
    ln_kernel<float><<<4096, blk, 0, stream>>>(tmpA, tmpB, nullptr, attoutB);

    // ---- FFN: ff1 full N=4096; ff2 split-K z=2 (res = attoutB bf16); LN2 sums ----
    mfma_gemm<unsigned short, float, 1, 0><<<dim3(32, 32), blk, 0, stream>>>(
        attoutB, D, W1b, D, b1, nullptr, nullptr, (const float*)nullptr,
        ff1, nullptr, nullptr, 4096, M, 4096, D);
    mfma_gemm<unsigned short, unsigned short, 0, 0><<<dim3(8, 32, 2), blk, 0, stream>>>(
        ff1, 4096, W2b, 4096, b2, nullptr, nullptr, attoutB, ff2a, ff2b, nullptr, D, M, D, 2048);
    ln_kernel<unsigned short><<<4096, blk, 0, stream>>>(ff2a, ff2b, (float*)d_out, nullptr);
}